// Round 15
// baseline (2427.706 us; speedup 1.0000x reference)
//
#include <hip/hip_runtime.h>
#include <hip/hip_bf16.h>
#include <math.h>

#define BB 512
#define LATENT 128
#define HID 256
#define GDIM 768
#define NMAX 50
#define NHEADS 4
#define HD 64
#define NPAIRS 1225

// ---------------------------------------------------------------------------
// offs[b] = exclusive prefix sum of nn; offs[512] = total live rows (Nlive)
__global__ __launch_bounds__(512) void k_offs(const int* __restrict__ nn,
                                              int* __restrict__ offs)
{
    __shared__ int s[512];
    const int tid = threadIdx.x;
    s[tid] = nn[tid];
    __syncthreads();
    for (int d = 1; d < 512; d <<= 1) {
        int v = (tid >= d) ? s[tid - d] : 0;
        __syncthreads();
        s[tid] += v;
        __syncthreads();
    }
    if (tid == 0) offs[0] = 0;
    offs[tid + 1] = s[tid];
}

// ---------------------------------------------------------------------------
// Tiled GEMM, double-buffered LDS: O[r][oc] = sum_k X[r][k]*W[oc][k] (+bias)
// Block tile 64x128, 256 threads, thread tile 4x8, f64 accumulate.
// Rows are COMPACTED live rows; NLIVE => early-exit blocks beyond *nlivep.
template<int KD, bool XF64, bool OF64, bool BIAS, bool NLIVE>
__global__ __launch_bounds__(256) void k_gemm5(
        const void* __restrict__ Xv, long xstride, int xzoff,
        const int* __restrict__ nlivep,
        const float* __restrict__ W, int wstride, long wzoff,
        const float* __restrict__ bias,
        void* __restrict__ Ov, long ostride, int ozoff)
{
    const int rb = blockIdx.x * 64;
    if (NLIVE) { if (rb >= *nlivep) return; }
    __shared__ double xs[2][64][17];
    __shared__ float  wsm[2][128][17];
    const int ob = blockIdx.y * 128;
    const int zid = blockIdx.z;
    const int tid = threadIdx.x;
    const int ty = tid >> 4, tx = tid & 15;
    const int lr  = tid >> 2;            // X tile row 0..63
    const int lk  = (tid & 3) * 4;       // X k offset 0,4,8,12
    const int lr2 = tid >> 1;            // W tile row 0..127
    const int lk2 = (tid & 1) * 8;       // W k offset 0/8
    const int xrow = rb + lr;

    const double* xp64 = nullptr; const float* xp32 = nullptr;
    if (XF64) xp64 = (const double*)Xv + (size_t)xrow * xstride + zid * (long)xzoff;
    else      xp32 = (const float*)Xv + (size_t)xrow * xstride + zid * (long)xzoff;
    const float* wp = W + (size_t)zid * wzoff + (size_t)(ob + lr2) * wstride + lk2;

    double xstg[4]; float wstg[8];

#define GEMM_LOAD(K0)                                                          \
    {                                                                          \
        if (XF64) {                                                            \
            _Pragma("unroll")                                                  \
            for (int u = 0; u < 4; ++u) xstg[u] = xp64[(K0) + lk + u];         \
        } else {                                                               \
            _Pragma("unroll")                                                  \
            for (int u = 0; u < 4; ++u) xstg[u] = (double)xp32[(K0) + lk + u]; \
        }                                                                      \
        _Pragma("unroll")                                                      \
        for (int u = 0; u < 8; ++u) wstg[u] = wp[(K0) + u];                    \
    }

#define GEMM_WRITE(BUF)                                                        \
    {                                                                          \
        _Pragma("unroll")                                                      \
        for (int u = 0; u < 4; ++u) xs[(BUF)][lr][lk + u] = xstg[u];           \
        _Pragma("unroll")                                                      \
        for (int u = 0; u < 8; ++u) wsm[(BUF)][lr2][lk2 + u] = wstg[u];        \
    }

    double acc[4][8];
    #pragma unroll
    for (int i = 0; i < 4; ++i)
        #pragma unroll
        for (int j = 0; j < 8; ++j) acc[i][j] = 0.0;

    constexpr int NC = KD / 16;
    GEMM_LOAD(0);
    GEMM_WRITE(0);
    for (int c = 0; c < NC; ++c) {
        __syncthreads();
        if (c + 1 < NC) GEMM_LOAD((c + 1) * 16);
        const int bi = c & 1;
        #pragma unroll
        for (int kk = 0; kk < 16; ++kk) {
            double wv[8];
            #pragma unroll
            for (int j = 0; j < 8; ++j) wv[j] = (double)wsm[bi][j * 16 + tx][kk];
            #pragma unroll
            for (int i = 0; i < 4; ++i) {
                double xr = xs[bi][ty * 4 + i][kk];
                #pragma unroll
                for (int j = 0; j < 8; ++j) acc[i][j] += xr * wv[j];
            }
        }
        if (c + 1 < NC) GEMM_WRITE((c + 1) & 1);
    }
    #pragma unroll
    for (int i = 0; i < 4; ++i) {
        size_t row = rb + ty * 4 + i;
        #pragma unroll
        for (int j = 0; j < 8; ++j) {
            int ocg = ob + j * 16 + tx;
            double v = acc[i][j];
            if (BIAS) v += (double)bias[ocg];
            size_t o = row * ostride + (size_t)zid * ozoff + ocg;
            if (OF64) ((double*)Ov)[o] = v;
            else      ((float*)Ov)[o] = (float)v;
        }
    }
#undef GEMM_LOAD
#undef GEMM_WRITE
}

// ---------------------------------------------------------------------------
// Ap[t][g] = sum_i pos[t][i] * w_ih0[g][i]   (50 x 768, f64, no bias)
__global__ __launch_bounds__(256) void k_ap(
        const float* __restrict__ pos, const float* __restrict__ w,
        double* __restrict__ Ap)
{
    __shared__ float ps[LATENT];
    const int t = blockIdx.x;
    const int tid = threadIdx.x;
    if (tid < LATENT) ps[tid] = pos[(size_t)t * LATENT + tid];
    __syncthreads();
    for (int g = tid; g < GDIM; g += 256) {
        double acc = 0.0;
        const float* wr = w + (size_t)g * LATENT;
        for (int i = 0; i < LATENT; ++i) acc += (double)ps[i] * (double)wr[i];
        Ap[(size_t)t * GDIM + g] = acc;
    }
}

// ---------------------------------------------------------------------------
// pack w_hh f32 [768][256] -> wAll[k][g*256+f]  (so MAC col index == tid)
__global__ __launch_bounds__(256) void k_pack_all(
        const float* __restrict__ whh, float* __restrict__ wAll)
{
    int idx = blockIdx.x * 256 + threadIdx.x;   // 196608
    int k = idx / GDIM, col = idx % GDIM;
    wAll[idx] = whh[(size_t)col * HID + k];     // col = g*256+f == whh row
}

// ---------------------------------------------------------------------------
// Persistent GRU, LDS-staged weights (k_gemm5 double-buffer pattern).
// grid 256 x 768 threads. Block owns 2 batches. MAC thread = (g=tid>>8, f):
// accumulates full k=0..255 ascending (R4-proven grouping) for both batches,
// weights read from LDS chunk wbuf[16][768] (col index == tid), hs via one
// double2 broadcast. Gate thread (tid<512) = (b=tid>>8, f) via red[3][2][256].
// Chunk pipeline: [barrier; load c+1 -> regs; MAC c; write c+1 -> LDS],
// wrapping to chunk 0 for the next timestep. Early-freeze to tmax.
// XGMODE 0: x-gates from compacted xg rows. XGMODE 1: Az+Ap+b_ih.
template<int XGMODE>
__global__ __launch_bounds__(768) void k_gru10(
        const double* __restrict__ xg,            // XGMODE0: xg; XGMODE1: Az
        const double* __restrict__ Ap,
        const float* __restrict__ bih,
        const int* __restrict__ nn,
        const int* __restrict__ offs,
        double* __restrict__ hout,
        const float* __restrict__ wAll, const float* __restrict__ bhh)
{
    const int tid = threadIdx.x;
    const int gf = tid & 255;            // feature (all threads)
    const int gb = tid >> 8;             // MAC: gate idx 0..2; gate phase: batch 0..1
    const int b0 = blockIdx.x * 2;

    __shared__ double hs[HID][2];        // 4 KB   [k][b]
    __shared__ double red[3][2][HID];    // 12 KB  [gate][b][f]
    __shared__ float  wbuf[2][16 * GDIM]; // 96 KB

    if (tid < 512) hs[gf][gb] = 0.0;

    const int nn0 = nn[b0], nn1 = nn[b0 + 1];
    const int tmax = nn0 > nn1 ? nn0 : nn1;

    int nnb = 0;
    double br = 0, bz = 0, bn = 0, bihr = 0, bihz = 0, bihn = 0;
    const double* xbase = nullptr;
    double* hob = nullptr;
    if (tid < 512) {
        const int bg = b0 + gb;
        nnb = (gb == 0) ? nn0 : nn1;
        br = (double)bhh[gf]; bz = (double)bhh[HID + gf]; bn = (double)bhh[2 * HID + gf];
        if (XGMODE == 1) {
            bihr = (double)bih[gf]; bihz = (double)bih[HID + gf]; bihn = (double)bih[2 * HID + gf];
            xbase = xg + (size_t)bg * GDIM + gf;
        } else {
            xbase = xg + (size_t)offs[bg] * GDIM + gf;
        }
        hob = hout + (size_t)offs[bg] * HID + gf;
    }

    // staging prologue: chunk 0 -> wbuf[0]
    const float4* wsrc = (const float4*)wAll;    // chunk c = float4 [c*3072, +3072)
    float4 stg[4];
    #pragma unroll
    for (int r = 0; r < 4; ++r) stg[r] = wsrc[r * 768 + tid];
    #pragma unroll
    for (int r = 0; r < 4; ++r) ((float4*)&wbuf[0][0])[r * 768 + tid] = stg[r];

    for (int t = 0; t < tmax; ++t) {
        const bool act = (tid < 512) && (t < nnb);
        // x-gate values, issued early (consumed in gate phase)
        double xr = 0, xz = 0, xn_ = 0;
        if (act) {
            if (XGMODE == 0) {
                const double* x = xbase + (size_t)t * GDIM;
                xr = x[0]; xz = x[HID]; xn_ = x[2 * HID];
            } else {
                const double* ap = Ap + (size_t)t * GDIM + gf;
                xr  = xbase[0]       + ap[0]       + bihr;
                xz  = xbase[HID]     + ap[HID]     + bihz;
                xn_ = xbase[2 * HID] + ap[2 * HID] + bihn;
            }
        }

        double a0 = 0.0, a1 = 0.0;
        for (int c = 0; c < 16; ++c) {
            __syncthreads();             // chunk c resident in wbuf[c&1]
            const int cn = (c + 1) & 15; // next chunk (wraps for next timestep)
            #pragma unroll
            for (int r = 0; r < 4; ++r) stg[r] = wsrc[cn * 3072 + r * 768 + tid];
            const float* wb = &wbuf[c & 1][0];
            const int k0 = c * 16;
            #pragma unroll
            for (int kk = 0; kk < 16; ++kk) {
                double w = (double)wb[kk * GDIM + tid];
                double2 hv = *(const double2*)&hs[k0 + kk][0];
                a0 += hv.x * w;
                a1 += hv.y * w;
            }
            #pragma unroll
            for (int r = 0; r < 4; ++r)
                ((float4*)&wbuf[(c + 1) & 1][0])[r * 768 + tid] = stg[r];
        }
        red[gb][0][gf] = a0;
        red[gb][1][gf] = a1;
        __syncthreads();

        if (act) {
            double ar = red[0][gb][gf];
            double az = red[1][gb][gf];
            double an = red[2][gb][gf];
            double hp = hs[gf][gb];
            double rg = 1.0 / (1.0 + exp(-(xr + ar + br)));
            double zg = 1.0 / (1.0 + exp(-(xz + az + bz)));
            double ng = tanh(xn_ + rg * (an + bn));
            double hn = (1.0 - zg) * ng + zg * hp;
            hs[gf][gb] = hn;
            hob[(size_t)t * HID] = hn;
        }
        // next timestep's first chunk barrier separates hs writes from MAC reads
    }
}

// ---------------------------------------------------------------------------
// WQ[g][h] = sum_o attn_in_w[g][o] * proj[o][h]   (768x256 f32)
__global__ __launch_bounds__(256) void k_wq(
        const float* __restrict__ aiw, const float* __restrict__ proj,
        float* __restrict__ WQ)
{
    __shared__ float arow[HID];
    int g = blockIdx.x, h = threadIdx.x;
    arow[h] = aiw[(size_t)g * HID + h];
    __syncthreads();
    double acc = 0.0;
    for (int o = 0; o < HID; ++o) acc += (double)arow[o] * (double)proj[(size_t)o * HID + h];
    WQ[(size_t)g * HID + h] = (float)acc;
}

// M[h][k][d] = sum_m wo[m][h*64+d] * w1[k][m]   (4x256x64 f32)
__global__ __launch_bounds__(256) void k_m(
        const float* __restrict__ wo, const float* __restrict__ w1,
        float* __restrict__ M)
{
    __shared__ float w1row[HID];
    int k = blockIdx.x, hd = threadIdx.x;
    w1row[hd] = w1[(size_t)k * HID + hd];
    __syncthreads();
    double acc = 0.0;
    for (int m = 0; m < HID; ++m) acc += (double)w1row[m] * (double)wo[(size_t)m * HID + hd];
    M[(((size_t)(hd >> 6)) * HID + k) * HD + (hd & 63)] = (float)acc;
}

// c[k] = sum_m attn_out_b[m]*mlp_w1[k,m] + mlp_b1[k]
__global__ void k_const(const float* __restrict__ ob, const float* __restrict__ w1,
                        const float* __restrict__ b1, double* __restrict__ c)
{
    int k = threadIdx.x;
    double acc = 0.0;
    for (int m = 0; m < HID; ++m) acc += (double)ob[m] * (double)w1[k * HID + m];
    c[k] = acc + (double)b1[k];
}

// ---------------------------------------------------------------------------
// Pairs: block per (b,i); wave per j (stride 4). Compacted rows offs[b]+n.
__global__ __launch_bounds__(256) void k_pairs3(
        const float* __restrict__ QKV, const float* __restrict__ G,
        const double* __restrict__ c,
        const int* __restrict__ nn, const int* __restrict__ offs,
        const float* __restrict__ gum,
        const float* __restrict__ w2, const float* __restrict__ b2,
        float* __restrict__ adj)
{
    const int bi = blockIdx.x;
    const int b = bi / (NMAX - 1);
    const int i = bi % (NMAX - 1);
    const int nnb = nn[b];
    if (i >= nnb - 1) return;
    const int tid = threadIdx.x;
    const int lane = tid & 63;
    const int wave = tid >> 6;
    const int ofb = offs[b];
    const size_t rowi = (size_t)(ofb + i);

    double cw[4], w2r[4];
    float gir[4][4];
    #pragma unroll
    for (int q = 0; q < 4; ++q) {
        int k = lane + 64 * q;
        cw[q] = c[k];
        w2r[q] = (double)w2[k] - (double)w2[HID + k];
        #pragma unroll
        for (int h = 0; h < 4; ++h) gir[q][h] = G[rowi * 1024 + h * HID + k];
    }
    const int sh = lane >> 4, sd = (lane & 15) * 4;
    const float4 qv  = *(const float4*)&QKV[rowi * GDIM + sh * HD + sd];
    const float4 kv0 = *(const float4*)&QKV[rowi * GDIM + HID + sh * HD + sd];
    double s0 = (double)qv.x * kv0.x + (double)qv.y * kv0.y
              + (double)qv.z * kv0.z + (double)qv.w * kv0.w;
    #pragma unroll
    for (int m = 1; m < 16; m <<= 1) s0 += __shfl_xor(s0, m, 64);
    s0 *= 0.125;
    const double b2d = (double)b2[0] - (double)b2[1];

    for (int j = i + 1 + wave; j < nnb; j += 4) {
        const size_t rowj = (size_t)(ofb + j);
        const float4 kv = *(const float4*)&QKV[rowj * GDIM + HID + sh * HD + sd];
        double s1 = (double)qv.x * kv.x + (double)qv.y * kv.y
                  + (double)qv.z * kv.z + (double)qv.w * kv.w;
        #pragma unroll
        for (int m = 1; m < 16; m <<= 1) s1 += __shfl_xor(s1, m, 64);
        s1 *= 0.125;
        double mx = fmax(s0, s1);
        double e0 = exp(s0 - mx), e1 = exp(s1 - mx);
        double inv = 1.0 / (e0 + e1);
        double a0 = e0 * inv, a1 = e1 * inv;
        double a0h[4], a1h[4];
        #pragma unroll
        for (int h = 0; h < 4; ++h) {
            a0h[h] = __shfl(a0, h * 16, 64);
            a1h[h] = __shfl(a1, h * 16, 64);
        }
        double dsum = 0.0;
        #pragma unroll
        for (int q = 0; q < 4; ++q) {
            int k = lane + 64 * q;
            double pre = cw[q];
            #pragma unroll
            for (int h = 0; h < 4; ++h)
                pre += a0h[h] * (double)gir[q][h]
                     + a1h[h] * (double)G[rowj * 1024 + h * HID + k];
            if (pre > 0.0) dsum += pre * w2r[q];
        }
        #pragma unroll
        for (int m = 1; m < 64; m <<= 1) dsum += __shfl_xor(dsum, m, 64);
        if (lane == 0) {
            int p_idx = i * (2 * NMAX - i - 1) / 2 + (j - i - 1);
            const float* gp = gum + ((size_t)b * NPAIRS + p_idx) * 2;
            double d = dsum + b2d + (double)gp[0] - (double)gp[1];
            if (d >= 0.0) {
                adj[(size_t)b * NMAX * NMAX + i * NMAX + j] = 1.0f;
                adj[(size_t)b * NMAX * NMAX + j * NMAX + i] = 1.0f;
            }
        }
    }
}

__global__ void k_ws_too_small(float* adj) { adj[0] = 2.0f; }

// ---------------------------------------------------------------------------
extern "C" void kernel_launch(void* const* d_in, const int* in_sizes, int n_in,
                              void* d_out, int out_size, void* d_ws, size_t ws_size,
                              hipStream_t stream)
{
    const float* z          = (const float*)d_in[0];
    const int*   nn         = (const int*)d_in[1];
    const float* pos        = (const float*)d_in[3];
    const float* w_ih0      = (const float*)d_in[4];
    const float* w_hh0      = (const float*)d_in[5];
    const float* b_ih0      = (const float*)d_in[6];
    const float* b_hh0      = (const float*)d_in[7];
    const float* w_ih1      = (const float*)d_in[8];
    const float* w_hh1      = (const float*)d_in[9];
    const float* b_ih1      = (const float*)d_in[10];
    const float* b_hh1      = (const float*)d_in[11];
    const float* proj       = (const float*)d_in[12];
    const float* attn_in_w  = (const float*)d_in[13];
    const float* attn_in_b  = (const float*)d_in[14];
    const float* attn_out_w = (const float*)d_in[15];
    const float* attn_out_b = (const float*)d_in[16];
    const float* mlp_w1     = (const float*)d_in[17];
    const float* mlp_b1     = (const float*)d_in[18];
    const float* mlp_w2     = (const float*)d_in[19];
    const float* mlp_b2     = (const float*)d_in[20];
    const float* gum        = (const float*)d_in[21];

    float* adj = (float*)d_out;
    hipMemsetAsync(adj, 0, (size_t)out_size * sizeof(float), stream);

    // Compacted region map — NO live-data aliasing:
    //  offs  @0          (4 KB, persists whole call)
    //  xg    @4096       157286400   | post-GRU1 overlay: qkv f32 @4096,
    //                                  G f32 @78647296
    //  h0/h1 @157290496  52428800
    //  wAll0 @209719296  786432 | wAll1 @210505728  786432
    //  WQ    @211292160  786432 | M @212078592 262144 | cbf @212340736 2048
    //  Az    @212342784  3145728 | Ap @215488512 307200  (ends 215795712)
    const size_t NEED = 215795712;
    if (ws_size < NEED) { hipLaunchKernelGGL(k_ws_too_small, dim3(1), dim3(1), 0, stream, adj); return; }

    char* ws = (char*)d_ws;
    int*    offs  = (int*)(ws);
    double* xg    = (double*)(ws + 4096);
    double* h01   = (double*)(ws + 157290496);
    float*  wAll0 = (float*)(ws + 209719296);
    float*  wAll1 = (float*)(ws + 210505728);
    float*  WQ    = (float*)(ws + 211292160);
    float*  M     = (float*)(ws + 212078592);
    double* cbf   = (double*)(ws + 212340736);
    double* Az    = (double*)(ws + 212342784);
    double* Ap    = (double*)(ws + 215488512);
    float*  qkv   = (float*)(ws + 4096);
    float*  G     = (float*)(ws + 78647296);
    const int* nlivep = offs + 512;

    // 0) prefix-sum of nn -> offs
    hipLaunchKernelGGL(k_offs, dim3(1), dim3(512), 0, stream, nn, offs);
    // 1) separable layer-0 input gates: Az = z@w_ih0^T (512x768), Ap = pos@w_ih0^T
    hipLaunchKernelGGL((k_gemm5<LATENT, false, true, false, false>), dim3(8, 6), dim3(256), 0, stream,
                       (const void*)z, (long)LATENT, 0, nullptr,
                       w_ih0, LATENT, 0L, (const float*)nullptr,
                       (void*)Az, (long)GDIM, 0);
    hipLaunchKernelGGL(k_ap, dim3(NMAX), dim3(256), 0, stream, pos, w_ih0, Ap);
    // 2) GRU layer 0 (LDS-staged weights, early-freeze, compacted h0)
    hipLaunchKernelGGL(k_pack_all, dim3(768), dim3(256), 0, stream, w_hh0, wAll0);
    hipLaunchKernelGGL((k_gru10<1>), dim3(256), dim3(768), 0, stream,
                       Az, Ap, b_ih0, nn, offs, h01, wAll0, b_hh0);
    // 3) layer-1 input gates over compacted live rows only
    hipLaunchKernelGGL((k_gemm5<HID, true, true, true, true>), dim3(400, 6), dim3(256), 0, stream,
                       (const void*)h01, (long)HID, 0, nlivep,
                       w_ih1, HID, 0L, b_ih1, (void*)xg, (long)GDIM, 0);
    // 4) GRU layer 1 (h1 overwrites dead h0; reads compacted xg)
    hipLaunchKernelGGL(k_pack_all, dim3(768), dim3(256), 0, stream, w_hh1, wAll1);
    hipLaunchKernelGGL((k_gru10<0>), dim3(256), dim3(768), 0, stream,
                       xg, nullptr, nullptr, nn, offs, h01, wAll1, b_hh1);
    // 5) fused (proj @ attn_in_w), then qkv from compacted h1 (all rows live)
    hipLaunchKernelGGL(k_wq, dim3(768), dim3(256), 0, stream, attn_in_w, proj, WQ);
    hipLaunchKernelGGL((k_gemm5<HID, true, false, true, true>), dim3(400, 6), dim3(256), 0, stream,
                       (const void*)h01, (long)HID, 0, nlivep,
                       WQ, HID, 0L, attn_in_b, (void*)qkv, (long)GDIM, 0);
    // 6) M precompute + single fused G GEMM (grid.z = head, compacted rows)
    hipLaunchKernelGGL(k_m, dim3(256), dim3(256), 0, stream, attn_out_w, mlp_w1, M);
    hipLaunchKernelGGL(k_const, dim3(1), dim3(256), 0, stream, attn_out_b, mlp_w1, mlp_b1, cbf);
    hipLaunchKernelGGL((k_gemm5<HD, false, false, false, true>), dim3(400, 2, 4), dim3(256), 0, stream,
                       (const void*)(qkv + 2 * HID), (long)GDIM, HD, nlivep,
                       M, HD, (long)(HID * HD), (const float*)nullptr,
                       (void*)G, 1024L, HID);
    // 7) pairs (compacted row indexing)
    hipLaunchKernelGGL(k_pairs3, dim3(BB * (NMAX - 1)), dim3(256), 0, stream,
                       qkv, G, cbf, nn, offs, gum, mlp_w2, mlp_b2, adj);
}

// Round 16
// 1837.798 us; speedup vs baseline: 1.3210x; 1.3210x over previous
//
#include <hip/hip_runtime.h>
#include <hip/hip_bf16.h>
#include <math.h>

#define BB 512
#define LATENT 128
#define HID 256
#define GDIM 768
#define NMAX 50
#define NHEADS 4
#define HD 64
#define NPAIRS 1225

// ---------------------------------------------------------------------------
// offs[b] = exclusive prefix sum of nn; offs[512] = total live rows (Nlive)
__global__ __launch_bounds__(512) void k_offs(const int* __restrict__ nn,
                                              int* __restrict__ offs)
{
    __shared__ int s[512];
    const int tid = threadIdx.x;
    s[tid] = nn[tid];
    __syncthreads();
    for (int d = 1; d < 512; d <<= 1) {
        int v = (tid >= d) ? s[tid - d] : 0;
        __syncthreads();
        s[tid] += v;
        __syncthreads();
    }
    if (tid == 0) offs[0] = 0;
    offs[tid + 1] = s[tid];
}

// ---------------------------------------------------------------------------
// Tiled GEMM, double-buffered LDS: O[r][oc] = sum_k X[r][k]*W[oc][k] (+bias)
// Block tile 64x128, 256 threads, thread tile 4x8, f64 accumulate.
// Rows are COMPACTED live rows; NLIVE => early-exit blocks beyond *nlivep.
template<int KD, bool XF64, bool OF64, bool BIAS, bool NLIVE>
__global__ __launch_bounds__(256) void k_gemm5(
        const void* __restrict__ Xv, long xstride, int xzoff,
        const int* __restrict__ nlivep,
        const float* __restrict__ W, int wstride, long wzoff,
        const float* __restrict__ bias,
        void* __restrict__ Ov, long ostride, int ozoff)
{
    const int rb = blockIdx.x * 64;
    if (NLIVE) { if (rb >= *nlivep) return; }
    __shared__ double xs[2][64][17];
    __shared__ float  wsm[2][128][17];
    const int ob = blockIdx.y * 128;
    const int zid = blockIdx.z;
    const int tid = threadIdx.x;
    const int ty = tid >> 4, tx = tid & 15;
    const int lr  = tid >> 2;            // X tile row 0..63
    const int lk  = (tid & 3) * 4;       // X k offset 0,4,8,12
    const int lr2 = tid >> 1;            // W tile row 0..127
    const int lk2 = (tid & 1) * 8;       // W k offset 0/8
    const int xrow = rb + lr;

    const double* xp64 = nullptr; const float* xp32 = nullptr;
    if (XF64) xp64 = (const double*)Xv + (size_t)xrow * xstride + zid * (long)xzoff;
    else      xp32 = (const float*)Xv + (size_t)xrow * xstride + zid * (long)xzoff;
    const float* wp = W + (size_t)zid * wzoff + (size_t)(ob + lr2) * wstride + lk2;

    double xstg[4]; float wstg[8];

#define GEMM_LOAD(K0)                                                          \
    {                                                                          \
        if (XF64) {                                                            \
            _Pragma("unroll")                                                  \
            for (int u = 0; u < 4; ++u) xstg[u] = xp64[(K0) + lk + u];         \
        } else {                                                               \
            _Pragma("unroll")                                                  \
            for (int u = 0; u < 4; ++u) xstg[u] = (double)xp32[(K0) + lk + u]; \
        }                                                                      \
        _Pragma("unroll")                                                      \
        for (int u = 0; u < 8; ++u) wstg[u] = wp[(K0) + u];                    \
    }

#define GEMM_WRITE(BUF)                                                        \
    {                                                                          \
        _Pragma("unroll")                                                      \
        for (int u = 0; u < 4; ++u) xs[(BUF)][lr][lk + u] = xstg[u];           \
        _Pragma("unroll")                                                      \
        for (int u = 0; u < 8; ++u) wsm[(BUF)][lr2][lk2 + u] = wstg[u];        \
    }

    double acc[4][8];
    #pragma unroll
    for (int i = 0; i < 4; ++i)
        #pragma unroll
        for (int j = 0; j < 8; ++j) acc[i][j] = 0.0;

    constexpr int NC = KD / 16;
    GEMM_LOAD(0);
    GEMM_WRITE(0);
    for (int c = 0; c < NC; ++c) {
        __syncthreads();
        if (c + 1 < NC) GEMM_LOAD((c + 1) * 16);
        const int bi = c & 1;
        #pragma unroll
        for (int kk = 0; kk < 16; ++kk) {
            double wv[8];
            #pragma unroll
            for (int j = 0; j < 8; ++j) wv[j] = (double)wsm[bi][j * 16 + tx][kk];
            #pragma unroll
            for (int i = 0; i < 4; ++i) {
                double xr = xs[bi][ty * 4 + i][kk];
                #pragma unroll
                for (int j = 0; j < 8; ++j) acc[i][j] += xr * wv[j];
            }
        }
        if (c + 1 < NC) GEMM_WRITE((c + 1) & 1);
    }
    #pragma unroll
    for (int i = 0; i < 4; ++i) {
        size_t row = rb + ty * 4 + i;
        #pragma unroll
        for (int j = 0; j < 8; ++j) {
            int ocg = ob + j * 16 + tx;
            double v = acc[i][j];
            if (BIAS) v += (double)bias[ocg];
            size_t o = row * ostride + (size_t)zid * ozoff + ocg;
            if (OF64) ((double*)Ov)[o] = v;
            else      ((float*)Ov)[o] = (float)v;
        }
    }
#undef GEMM_LOAD
#undef GEMM_WRITE
}

// ---------------------------------------------------------------------------
// Ap[t][g] = sum_i pos[t][i] * w_ih0[g][i]   (50 x 768, f64, no bias)
__global__ __launch_bounds__(256) void k_ap(
        const float* __restrict__ pos, const float* __restrict__ w,
        double* __restrict__ Ap)
{
    __shared__ float ps[LATENT];
    const int t = blockIdx.x;
    const int tid = threadIdx.x;
    if (tid < LATENT) ps[tid] = pos[(size_t)t * LATENT + tid];
    __syncthreads();
    for (int g = tid; g < GDIM; g += 256) {
        double acc = 0.0;
        const float* wr = w + (size_t)g * LATENT;
        for (int i = 0; i < LATENT; ++i) acc += (double)ps[i] * (double)wr[i];
        Ap[(size_t)t * GDIM + g] = acc;
    }
}

// ---------------------------------------------------------------------------
// pack w_hh f32 [768][256] -> wRZ float2 [k][f] (r,z) and wN float [k][f]
__global__ __launch_bounds__(256) void k_pack_bat(
        const float* __restrict__ whh, float2* __restrict__ wRZ,
        float* __restrict__ wN)
{
    int k = blockIdx.x, f = threadIdx.x;
    float r = whh[(size_t)(0 * HID + f) * HID + k];
    float zz = whh[(size_t)(1 * HID + f) * HID + k];
    float n = whh[(size_t)(2 * HID + f) * HID + k];
    wRZ[(size_t)k * HID + f] = make_float2(r, zz);
    wN[(size_t)k * HID + f] = n;
}

// ---------------------------------------------------------------------------
// Persistent batch-sliced GRU: grid 256 x 1024 threads, BG=2, kq-split K.
// R16: DE-PHASED weight stream — block-dependent rotation of the k-quarter
// assignment (kqe) and within-quarter start offset (rot8) so concurrent
// blocks request DIFFERENT parts of the 786 KB weight stream instead of
// hammering the same 3 KB slice of L2 in lockstep (suspected L2 hotspot =
// the 2x gap vs BW floor). Quarter partials land in canonical red[kqe]
// slots; gate phase sums quarters in fixed ascending order (same as R11-14).
// Within-quarter rotation is a pure f64 regrouping (~1e-16 perturbation).
// Early-freeze to tmax; h stored COMPACTED at rows offs[bg]+t.
// XGMODE 0: x-gates from compacted xg rows. XGMODE 1: Az+Ap+b_ih.
template<int XGMODE>
__global__ __launch_bounds__(1024) void k_gru8(
        const double* __restrict__ xg,            // XGMODE0: xg; XGMODE1: Az
        const double* __restrict__ Ap,
        const float* __restrict__ bih,
        const int* __restrict__ nn,
        const int* __restrict__ offs,
        double* __restrict__ hout,
        const float2* __restrict__ wRZ, const float* __restrict__ wN,
        const float* __restrict__ bhh)
{
    const int tid = threadIdx.x;
    const int f  = tid & 255;
    const int kq = tid >> 8;             // 0..3
    const int b0 = blockIdx.x * 2;
    const int kqe  = (kq + (int)blockIdx.x) & 3;        // de-phased quarter
    const int rot8 = (((int)blockIdx.x >> 2) & 7) * 8;  // start offset in quarter

    __shared__ double hs[HID][2];        // 4 KB
    __shared__ double red[4][6][HID];    // 48 KB: [quarter][gate*2+b][f]

    if (kq < 2) hs[f][kq] = 0.0;

    const int nn0 = nn[b0], nn1 = nn[b0 + 1];
    const int tmax = nn0 > nn1 ? nn0 : nn1;

    const int bq = kq;                   // batch slot for gate phase
    const int bg = b0 + (kq < 2 ? kq : 0);
    const int nnb = (kq == 0) ? nn0 : ((kq == 1) ? nn1 : 0);
    const int offs_bg = offs[bg];
    double br = 0, bz = 0, bn = 0, bihr = 0, bihz = 0, bihn = 0;
    if (kq < 2) {
        br = (double)bhh[f]; bz = (double)bhh[HID + f]; bn = (double)bhh[2 * HID + f];
        if (XGMODE == 1) {
            bihr = (double)bih[f]; bihz = (double)bih[HID + f]; bihn = (double)bih[2 * HID + f];
        }
    }
    const float2* wrz = wRZ + (size_t)(kqe * 64) * HID + f;
    const float*  wn  = wN  + (size_t)(kqe * 64) * HID + f;
    const double* xbase = (XGMODE == 1)
        ? xg + (size_t)bg * GDIM + f
        : xg + (size_t)offs_bg * GDIM + f;
    double* hob = hout + (size_t)offs_bg * HID + f;
    const int kbase = kqe * 64;

    __syncthreads();

    for (int t = 0; t < tmax; ++t) {
        const bool act = (kq < 2) && (t < nnb);
        // x-gate values for (bg, f), active threads only, issued early
        double xr = 0, xz = 0, xn_ = 0;
        if (act) {
            if (XGMODE == 0) {
                const double* x = xbase + (size_t)t * GDIM;
                xr = x[0]; xz = x[HID]; xn_ = x[2 * HID];
            } else {
                const double* ap = Ap + (size_t)t * GDIM + f;
                xr  = xbase[0]       + ap[0]       + bihr;
                xz  = xbase[HID]     + ap[HID]     + bihz;
                xn_ = xbase[2 * HID] + ap[2 * HID] + bihn;
            }
        }

        // MAC: quarter kqe, both batches, k iterated rot8..63 then 0..rot8-1
        double a0 = 0, a1 = 0, a2 = 0, a3 = 0, a4 = 0, a5 = 0;
        const double2* hs2 = (const double2*)&hs[kbase][0];
        #pragma unroll 8
        for (int kk = rot8; kk < 64; ++kk) {
            float2 rz = wrz[(size_t)kk * HID];
            float  nw = wn[(size_t)kk * HID];
            double wrd = (double)rz.x, wzd = (double)rz.y, wnd = (double)nw;
            double2 hv = hs2[kk];
            a0 += hv.x * wrd; a1 += hv.y * wrd;
            a2 += hv.x * wzd; a3 += hv.y * wzd;
            a4 += hv.x * wnd; a5 += hv.y * wnd;
        }
        #pragma unroll 8
        for (int kk = 0; kk < rot8; ++kk) {
            float2 rz = wrz[(size_t)kk * HID];
            float  nw = wn[(size_t)kk * HID];
            double wrd = (double)rz.x, wzd = (double)rz.y, wnd = (double)nw;
            double2 hv = hs2[kk];
            a0 += hv.x * wrd; a1 += hv.y * wrd;
            a2 += hv.x * wzd; a3 += hv.y * wzd;
            a4 += hv.x * wnd; a5 += hv.y * wnd;
        }
        red[kqe][0][f] = a0; red[kqe][1][f] = a1;
        red[kqe][2][f] = a2; red[kqe][3][f] = a3;
        red[kqe][4][f] = a4; red[kqe][5][f] = a5;
        __syncthreads();

        if (act) {
            // sum quarters in fixed ascending order; gate eval for (bg, f)
            double ar = 0, az = 0, an = 0;
            #pragma unroll
            for (int qq = 0; qq < 4; ++qq) {
                ar += red[qq][0 * 2 + bq][f];
                az += red[qq][1 * 2 + bq][f];
                an += red[qq][2 * 2 + bq][f];
            }
            double hp = hs[f][bq];
            double rg = 1.0 / (1.0 + exp(-(xr + ar + br)));
            double zg = 1.0 / (1.0 + exp(-(xz + az + bz)));
            double ng = tanh(xn_ + rg * (an + bn));
            double hn = (1.0 - zg) * ng + zg * hp;
            hs[f][bq] = hn;
            hob[(size_t)t * HID] = hn;
        }
        __syncthreads();
    }
}

// ---------------------------------------------------------------------------
// WQ[g][h] = sum_o attn_in_w[g][o] * proj[o][h]   (768x256 f32)
__global__ __launch_bounds__(256) void k_wq(
        const float* __restrict__ aiw, const float* __restrict__ proj,
        float* __restrict__ WQ)
{
    __shared__ float arow[HID];
    int g = blockIdx.x, h = threadIdx.x;
    arow[h] = aiw[(size_t)g * HID + h];
    __syncthreads();
    double acc = 0.0;
    for (int o = 0; o < HID; ++o) acc += (double)arow[o] * (double)proj[(size_t)o * HID + h];
    WQ[(size_t)g * HID + h] = (float)acc;
}

// M[h][k][d] = sum_m wo[m][h*64+d] * w1[k][m]   (4x256x64 f32)
__global__ __launch_bounds__(256) void k_m(
        const float* __restrict__ wo, const float* __restrict__ w1,
        float* __restrict__ M)
{
    __shared__ float w1row[HID];
    int k = blockIdx.x, hd = threadIdx.x;
    w1row[hd] = w1[(size_t)k * HID + hd];
    __syncthreads();
    double acc = 0.0;
    for (int m = 0; m < HID; ++m) acc += (double)w1row[m] * (double)wo[(size_t)m * HID + hd];
    M[(((size_t)(hd >> 6)) * HID + k) * HD + (hd & 63)] = (float)acc;
}

// c[k] = sum_m attn_out_b[m]*mlp_w1[k,m] + mlp_b1[k]
__global__ void k_const(const float* __restrict__ ob, const float* __restrict__ w1,
                        const float* __restrict__ b1, double* __restrict__ c)
{
    int k = threadIdx.x;
    double acc = 0.0;
    for (int m = 0; m < HID; ++m) acc += (double)ob[m] * (double)w1[k * HID + m];
    c[k] = acc + (double)b1[k];
}

// ---------------------------------------------------------------------------
// Pairs: block per (b,i); wave per j (stride 4). Compacted rows offs[b]+n.
__global__ __launch_bounds__(256) void k_pairs3(
        const float* __restrict__ QKV, const float* __restrict__ G,
        const double* __restrict__ c,
        const int* __restrict__ nn, const int* __restrict__ offs,
        const float* __restrict__ gum,
        const float* __restrict__ w2, const float* __restrict__ b2,
        float* __restrict__ adj)
{
    const int bi = blockIdx.x;
    const int b = bi / (NMAX - 1);
    const int i = bi % (NMAX - 1);
    const int nnb = nn[b];
    if (i >= nnb - 1) return;
    const int tid = threadIdx.x;
    const int lane = tid & 63;
    const int wave = tid >> 6;
    const int ofb = offs[b];
    const size_t rowi = (size_t)(ofb + i);

    double cw[4], w2r[4];
    float gir[4][4];
    #pragma unroll
    for (int q = 0; q < 4; ++q) {
        int k = lane + 64 * q;
        cw[q] = c[k];
        w2r[q] = (double)w2[k] - (double)w2[HID + k];
        #pragma unroll
        for (int h = 0; h < 4; ++h) gir[q][h] = G[rowi * 1024 + h * HID + k];
    }
    const int sh = lane >> 4, sd = (lane & 15) * 4;
    const float4 qv  = *(const float4*)&QKV[rowi * GDIM + sh * HD + sd];
    const float4 kv0 = *(const float4*)&QKV[rowi * GDIM + HID + sh * HD + sd];
    double s0 = (double)qv.x * kv0.x + (double)qv.y * kv0.y
              + (double)qv.z * kv0.z + (double)qv.w * kv0.w;
    #pragma unroll
    for (int m = 1; m < 16; m <<= 1) s0 += __shfl_xor(s0, m, 64);
    s0 *= 0.125;
    const double b2d = (double)b2[0] - (double)b2[1];

    for (int j = i + 1 + wave; j < nnb; j += 4) {
        const size_t rowj = (size_t)(ofb + j);
        const float4 kv = *(const float4*)&QKV[rowj * GDIM + HID + sh * HD + sd];
        double s1 = (double)qv.x * kv.x + (double)qv.y * kv.y
                  + (double)qv.z * kv.z + (double)qv.w * kv.w;
        #pragma unroll
        for (int m = 1; m < 16; m <<= 1) s1 += __shfl_xor(s1, m, 64);
        s1 *= 0.125;
        double mx = fmax(s0, s1);
        double e0 = exp(s0 - mx), e1 = exp(s1 - mx);
        double inv = 1.0 / (e0 + e1);
        double a0 = e0 * inv, a1 = e1 * inv;
        double a0h[4], a1h[4];
        #pragma unroll
        for (int h = 0; h < 4; ++h) {
            a0h[h] = __shfl(a0, h * 16, 64);
            a1h[h] = __shfl(a1, h * 16, 64);
        }
        double dsum = 0.0;
        #pragma unroll
        for (int q = 0; q < 4; ++q) {
            int k = lane + 64 * q;
            double pre = cw[q];
            #pragma unroll
            for (int h = 0; h < 4; ++h)
                pre += a0h[h] * (double)gir[q][h]
                     + a1h[h] * (double)G[rowj * 1024 + h * HID + k];
            if (pre > 0.0) dsum += pre * w2r[q];
        }
        #pragma unroll
        for (int m = 1; m < 64; m <<= 1) dsum += __shfl_xor(dsum, m, 64);
        if (lane == 0) {
            int p_idx = i * (2 * NMAX - i - 1) / 2 + (j - i - 1);
            const float* gp = gum + ((size_t)b * NPAIRS + p_idx) * 2;
            double d = dsum + b2d + (double)gp[0] - (double)gp[1];
            if (d >= 0.0) {
                adj[(size_t)b * NMAX * NMAX + i * NMAX + j] = 1.0f;
                adj[(size_t)b * NMAX * NMAX + j * NMAX + i] = 1.0f;
            }
        }
    }
}

__global__ void k_ws_too_small(float* adj) { adj[0] = 2.0f; }

// ---------------------------------------------------------------------------
extern "C" void kernel_launch(void* const* d_in, const int* in_sizes, int n_in,
                              void* d_out, int out_size, void* d_ws, size_t ws_size,
                              hipStream_t stream)
{
    const float* z          = (const float*)d_in[0];
    const int*   nn         = (const int*)d_in[1];
    const float* pos        = (const float*)d_in[3];
    const float* w_ih0      = (const float*)d_in[4];
    const float* w_hh0      = (const float*)d_in[5];
    const float* b_ih0      = (const float*)d_in[6];
    const float* b_hh0      = (const float*)d_in[7];
    const float* w_ih1      = (const float*)d_in[8];
    const float* w_hh1      = (const float*)d_in[9];
    const float* b_ih1      = (const float*)d_in[10];
    const float* b_hh1      = (const float*)d_in[11];
    const float* proj       = (const float*)d_in[12];
    const float* attn_in_w  = (const float*)d_in[13];
    const float* attn_in_b  = (const float*)d_in[14];
    const float* attn_out_w = (const float*)d_in[15];
    const float* attn_out_b = (const float*)d_in[16];
    const float* mlp_w1     = (const float*)d_in[17];
    const float* mlp_b1     = (const float*)d_in[18];
    const float* mlp_w2     = (const float*)d_in[19];
    const float* mlp_b2     = (const float*)d_in[20];
    const float* gum        = (const float*)d_in[21];

    float* adj = (float*)d_out;
    hipMemsetAsync(adj, 0, (size_t)out_size * sizeof(float), stream);

    // Compacted region map — NO live-data aliasing:
    //  offs  @0          (4 KB, persists whole call)
    //  xg    @4096       157286400   | post-GRU1 overlay: qkv f32 @4096,
    //                                  G f32 @78647296
    //  h0/h1 @157290496  52428800
    //  wRZ0  @209719296  524288 | wN0 @210243584 262144
    //  wRZ1  @210505728  524288 | wN1 @211030016 262144
    //  WQ    @211292160  786432 | M @212078592 262144 | cbf @212340736 2048
    //  Az    @212342784  3145728 | Ap @215488512 307200  (ends 215795712)
    const size_t NEED = 215795712;
    if (ws_size < NEED) { hipLaunchKernelGGL(k_ws_too_small, dim3(1), dim3(1), 0, stream, adj); return; }

    char* ws = (char*)d_ws;
    int*    offs = (int*)(ws);
    double* xg   = (double*)(ws + 4096);
    double* h01  = (double*)(ws + 157290496);
    float2* wRZ0 = (float2*)(ws + 209719296);
    float*  wN0  = (float*)(ws + 210243584);
    float2* wRZ1 = (float2*)(ws + 210505728);
    float*  wN1  = (float*)(ws + 211030016);
    float*  WQ   = (float*)(ws + 211292160);
    float*  M    = (float*)(ws + 212078592);
    double* cbf  = (double*)(ws + 212340736);
    double* Az   = (double*)(ws + 212342784);
    double* Ap   = (double*)(ws + 215488512);
    float*  qkv  = (float*)(ws + 4096);
    float*  G    = (float*)(ws + 78647296);
    const int* nlivep = offs + 512;

    // 0) prefix-sum of nn -> offs
    hipLaunchKernelGGL(k_offs, dim3(1), dim3(512), 0, stream, nn, offs);
    // 1) separable layer-0 input gates: Az = z@w_ih0^T (512x768), Ap = pos@w_ih0^T
    hipLaunchKernelGGL((k_gemm5<LATENT, false, true, false, false>), dim3(8, 6), dim3(256), 0, stream,
                       (const void*)z, (long)LATENT, 0, nullptr,
                       w_ih0, LATENT, 0L, (const float*)nullptr,
                       (void*)Az, (long)GDIM, 0);
    hipLaunchKernelGGL(k_ap, dim3(NMAX), dim3(256), 0, stream, pos, w_ih0, Ap);
    // 2) GRU layer 0 (de-phased weight stream, early-freeze, compacted h0)
    hipLaunchKernelGGL(k_pack_bat, dim3(256), dim3(256), 0, stream, w_hh0, wRZ0, wN0);
    hipLaunchKernelGGL((k_gru8<1>), dim3(256), dim3(1024), 0, stream,
                       Az, Ap, b_ih0, nn, offs, h01, wRZ0, wN0, b_hh0);
    // 3) layer-1 input gates over compacted live rows only
    hipLaunchKernelGGL((k_gemm5<HID, true, true, true, true>), dim3(400, 6), dim3(256), 0, stream,
                       (const void*)h01, (long)HID, 0, nlivep,
                       w_ih1, HID, 0L, b_ih1, (void*)xg, (long)GDIM, 0);
    // 4) GRU layer 1 (h1 overwrites dead h0; reads compacted xg)
    hipLaunchKernelGGL(k_pack_bat, dim3(256), dim3(256), 0, stream, w_hh1, wRZ1, wN1);
    hipLaunchKernelGGL((k_gru8<0>), dim3(256), dim3(1024), 0, stream,
                       xg, nullptr, nullptr, nn, offs, h01, wRZ1, wN1, b_hh1);
    // 5) fused (proj @ attn_in_w), then qkv from compacted h1 (all rows live)
    hipLaunchKernelGGL(k_wq, dim3(768), dim3(256), 0, stream, attn_in_w, proj, WQ);
    hipLaunchKernelGGL((k_gemm5<HID, true, false, true, true>), dim3(400, 6), dim3(256), 0, stream,
                       (const void*)h01, (long)HID, 0, nlivep,
                       WQ, HID, 0L, attn_in_b, (void*)qkv, (long)GDIM, 0);
    // 6) M precompute + single fused G GEMM (grid.z = head, compacted rows)
    hipLaunchKernelGGL(k_m, dim3(256), dim3(256), 0, stream, attn_out_w, mlp_w1, M);
    hipLaunchKernelGGL(k_const, dim3(1), dim3(256), 0, stream, attn_out_b, mlp_w1, mlp_b1, cbf);
    hipLaunchKernelGGL((k_gemm5<HD, false, false, false, true>), dim3(400, 2, 4), dim3(256), 0, stream,
                       (const void*)(qkv + 2 * HID), (long)GDIM, HD, nlivep,
                       M, HD, (long)(HID * HD), (const float*)nullptr,
                       (void*)G, 1024L, HID);
    // 7) pairs (compacted row indexing)
    hipLaunchKernelGGL(k_pairs3, dim3(BB * (NMAX - 1)), dim3(256), 0, stream,
                       qkv, G, cbf, nn, offs, gum, mlp_w2, mlp_b2, adj);
}

// Round 17
// 1797.163 us; speedup vs baseline: 1.3509x; 1.0226x over previous
//
#include <hip/hip_runtime.h>
#include <hip/hip_bf16.h>
#include <math.h>

#define BB 512
#define LATENT 128
#define HID 256
#define GDIM 768
#define NMAX 50
#define NHEADS 4
#define HD 64
#define NPAIRS 1225

// ---------------------------------------------------------------------------
// offs[b] = exclusive prefix sum of nn; offs[512] = total live rows (Nlive)
__global__ __launch_bounds__(512) void k_offs(const int* __restrict__ nn,
                                              int* __restrict__ offs)
{
    __shared__ int s[512];
    const int tid = threadIdx.x;
    s[tid] = nn[tid];
    __syncthreads();
    for (int d = 1; d < 512; d <<= 1) {
        int v = (tid >= d) ? s[tid - d] : 0;
        __syncthreads();
        s[tid] += v;
        __syncthreads();
    }
    if (tid == 0) offs[0] = 0;
    offs[tid + 1] = s[tid];
}

// ---------------------------------------------------------------------------
// Bitonic sort of 512 batches by (nn, idx) ascending -> perm.
// Pairing sorted-adjacent batches minimizes sum over blocks of max(nn,nn).
__global__ __launch_bounds__(512) void k_sort(const int* __restrict__ nn,
                                              int* __restrict__ perm)
{
    __shared__ int s[512];
    const int tid = threadIdx.x;
    s[tid] = nn[tid] * 1024 + tid;       // composite key, fully deterministic
    __syncthreads();
    for (int k = 2; k <= 512; k <<= 1) {
        for (int j = k >> 1; j > 0; j >>= 1) {
            int ixj = tid ^ j;
            if (ixj > tid) {
                int a = s[tid], b = s[ixj];
                bool up = (tid & k) == 0;
                if (up ? (a > b) : (a < b)) { s[tid] = b; s[ixj] = a; }
            }
            __syncthreads();
        }
    }
    perm[tid] = s[tid] & 1023;
}

// ---------------------------------------------------------------------------
// Tiled GEMM, double-buffered LDS: O[r][oc] = sum_k X[r][k]*W[oc][k] (+bias)
// Block tile 64x128, 256 threads, thread tile 4x8, f64 accumulate.
// Rows are COMPACTED live rows; NLIVE => early-exit blocks beyond *nlivep.
template<int KD, bool XF64, bool OF64, bool BIAS, bool NLIVE>
__global__ __launch_bounds__(256) void k_gemm5(
        const void* __restrict__ Xv, long xstride, int xzoff,
        const int* __restrict__ nlivep,
        const float* __restrict__ W, int wstride, long wzoff,
        const float* __restrict__ bias,
        void* __restrict__ Ov, long ostride, int ozoff)
{
    const int rb = blockIdx.x * 64;
    if (NLIVE) { if (rb >= *nlivep) return; }
    __shared__ double xs[2][64][17];
    __shared__ float  wsm[2][128][17];
    const int ob = blockIdx.y * 128;
    const int zid = blockIdx.z;
    const int tid = threadIdx.x;
    const int ty = tid >> 4, tx = tid & 15;
    const int lr  = tid >> 2;            // X tile row 0..63
    const int lk  = (tid & 3) * 4;       // X k offset 0,4,8,12
    const int lr2 = tid >> 1;            // W tile row 0..127
    const int lk2 = (tid & 1) * 8;       // W k offset 0/8
    const int xrow = rb + lr;

    const double* xp64 = nullptr; const float* xp32 = nullptr;
    if (XF64) xp64 = (const double*)Xv + (size_t)xrow * xstride + zid * (long)xzoff;
    else      xp32 = (const float*)Xv + (size_t)xrow * xstride + zid * (long)xzoff;
    const float* wp = W + (size_t)zid * wzoff + (size_t)(ob + lr2) * wstride + lk2;

    double xstg[4]; float wstg[8];

#define GEMM_LOAD(K0)                                                          \
    {                                                                          \
        if (XF64) {                                                            \
            _Pragma("unroll")                                                  \
            for (int u = 0; u < 4; ++u) xstg[u] = xp64[(K0) + lk + u];         \
        } else {                                                               \
            _Pragma("unroll")                                                  \
            for (int u = 0; u < 4; ++u) xstg[u] = (double)xp32[(K0) + lk + u]; \
        }                                                                      \
        _Pragma("unroll")                                                      \
        for (int u = 0; u < 8; ++u) wstg[u] = wp[(K0) + u];                    \
    }

#define GEMM_WRITE(BUF)                                                        \
    {                                                                          \
        _Pragma("unroll")                                                      \
        for (int u = 0; u < 4; ++u) xs[(BUF)][lr][lk + u] = xstg[u];           \
        _Pragma("unroll")                                                      \
        for (int u = 0; u < 8; ++u) wsm[(BUF)][lr2][lk2 + u] = wstg[u];        \
    }

    double acc[4][8];
    #pragma unroll
    for (int i = 0; i < 4; ++i)
        #pragma unroll
        for (int j = 0; j < 8; ++j) acc[i][j] = 0.0;

    constexpr int NC = KD / 16;
    GEMM_LOAD(0);
    GEMM_WRITE(0);
    for (int c = 0; c < NC; ++c) {
        __syncthreads();
        if (c + 1 < NC) GEMM_LOAD((c + 1) * 16);
        const int bi = c & 1;
        #pragma unroll
        for (int kk = 0; kk < 16; ++kk) {
            double wv[8];
            #pragma unroll
            for (int j = 0; j < 8; ++j) wv[j] = (double)wsm[bi][j * 16 + tx][kk];
            #pragma unroll
            for (int i = 0; i < 4; ++i) {
                double xr = xs[bi][ty * 4 + i][kk];
                #pragma unroll
                for (int j = 0; j < 8; ++j) acc[i][j] += xr * wv[j];
            }
        }
        if (c + 1 < NC) GEMM_WRITE((c + 1) & 1);
    }
    #pragma unroll
    for (int i = 0; i < 4; ++i) {
        size_t row = rb + ty * 4 + i;
        #pragma unroll
        for (int j = 0; j < 8; ++j) {
            int ocg = ob + j * 16 + tx;
            double v = acc[i][j];
            if (BIAS) v += (double)bias[ocg];
            size_t o = row * ostride + (size_t)zid * ozoff + ocg;
            if (OF64) ((double*)Ov)[o] = v;
            else      ((float*)Ov)[o] = (float)v;
        }
    }
#undef GEMM_LOAD
#undef GEMM_WRITE
}

// ---------------------------------------------------------------------------
// Ap[t][g] = sum_i pos[t][i] * w_ih0[g][i]   (50 x 768, f64, no bias)
__global__ __launch_bounds__(256) void k_ap(
        const float* __restrict__ pos, const float* __restrict__ w,
        double* __restrict__ Ap)
{
    __shared__ float ps[LATENT];
    const int t = blockIdx.x;
    const int tid = threadIdx.x;
    if (tid < LATENT) ps[tid] = pos[(size_t)t * LATENT + tid];
    __syncthreads();
    for (int g = tid; g < GDIM; g += 256) {
        double acc = 0.0;
        const float* wr = w + (size_t)g * LATENT;
        for (int i = 0; i < LATENT; ++i) acc += (double)ps[i] * (double)wr[i];
        Ap[(size_t)t * GDIM + g] = acc;
    }
}

// ---------------------------------------------------------------------------
// pack w_hh f32 [768][256] -> wRZ float2 [k][f] (r,z) and wN float [k][f]
__global__ __launch_bounds__(256) void k_pack_bat(
        const float* __restrict__ whh, float2* __restrict__ wRZ,
        float* __restrict__ wN)
{
    int k = blockIdx.x, f = threadIdx.x;
    float r = whh[(size_t)(0 * HID + f) * HID + k];
    float zz = whh[(size_t)(1 * HID + f) * HID + k];
    float n = whh[(size_t)(2 * HID + f) * HID + k];
    wRZ[(size_t)k * HID + f] = make_float2(r, zz);
    wN[(size_t)k * HID + f] = n;
}

// ---------------------------------------------------------------------------
// Persistent batch-sliced GRU (R13-proven body): grid 256 x 1024, BG=2,
// kq-split K, early-freeze to tmax, compacted h at rows offs[bg]+t.
// R17: block processes batches (perm[2*bid], perm[2*bid+1]) — nn-sorted
// adjacent pairing cuts E[tmax] 33.8 -> ~26 (-22% weight traffic).
// Per-batch arithmetic and storage identical -> bitwise-same live h.
// XGMODE 0: x-gates from compacted xg rows. XGMODE 1: Az+Ap+b_ih.
template<int XGMODE>
__global__ __launch_bounds__(1024) void k_gru8(
        const double* __restrict__ xg,            // XGMODE0: xg; XGMODE1: Az
        const double* __restrict__ Ap,
        const float* __restrict__ bih,
        const int* __restrict__ nn,
        const int* __restrict__ offs,
        const int* __restrict__ perm,
        double* __restrict__ hout,
        const float2* __restrict__ wRZ, const float* __restrict__ wN,
        const float* __restrict__ bhh)
{
    const int tid = threadIdx.x;
    const int f  = tid & 255;
    const int kq = tid >> 8;             // 0..3
    const int bA = perm[2 * blockIdx.x];
    const int bB = perm[2 * blockIdx.x + 1];

    __shared__ double hs[HID][2];        // 4 KB
    __shared__ double red[4][6][HID];    // 48 KB: [kq][gate*2+b][f]

    if (kq < 2) hs[f][kq] = 0.0;

    const int nn0 = nn[bA], nn1 = nn[bB];
    const int tmax = nn0 > nn1 ? nn0 : nn1;

    const int bq = kq;                   // batch slot for gate phase
    const int bg = (kq == 1) ? bB : bA;  // kq0 -> bA, kq1 -> bB (kq>=2 unused)
    const int nnb = (kq == 0) ? nn0 : ((kq == 1) ? nn1 : 0);
    const int offs_bg = offs[bg];
    double br = 0, bz = 0, bn = 0, bihr = 0, bihz = 0, bihn = 0;
    if (kq < 2) {
        br = (double)bhh[f]; bz = (double)bhh[HID + f]; bn = (double)bhh[2 * HID + f];
        if (XGMODE == 1) {
            bihr = (double)bih[f]; bihz = (double)bih[HID + f]; bihn = (double)bih[2 * HID + f];
        }
    }
    const float2* wrz = wRZ + (size_t)(kq * 64) * HID + f;
    const float*  wn  = wN  + (size_t)(kq * 64) * HID + f;
    const double* xbase = (XGMODE == 1)
        ? xg + (size_t)bg * GDIM + f
        : xg + (size_t)offs_bg * GDIM + f;
    double* hob = hout + (size_t)offs_bg * HID + f;
    const int kbase = kq * 64;

    __syncthreads();

    for (int t = 0; t < tmax; ++t) {
        const bool act = (kq < 2) && (t < nnb);
        // x-gate values for (bg, f), active threads only, issued early
        double xr = 0, xz = 0, xn_ = 0;
        if (act) {
            if (XGMODE == 0) {
                const double* x = xbase + (size_t)t * GDIM;
                xr = x[0]; xz = x[HID]; xn_ = x[2 * HID];
            } else {
                const double* ap = Ap + (size_t)t * GDIM + f;
                xr  = xbase[0]       + ap[0]       + bihr;
                xz  = xbase[HID]     + ap[HID]     + bihz;
                xn_ = xbase[2 * HID] + ap[2 * HID] + bihn;
            }
        }

        // MAC: K-quarter kq, both batches. a[gate*2+b]
        double a0 = 0, a1 = 0, a2 = 0, a3 = 0, a4 = 0, a5 = 0;
        #pragma unroll 8
        for (int kk = 0; kk < 64; ++kk) {
            float2 rz = wrz[(size_t)kk * HID];
            float  nw = wn[(size_t)kk * HID];
            double wrd = (double)rz.x, wzd = (double)rz.y, wnd = (double)nw;
            double h0 = hs[kbase + kk][0], h1 = hs[kbase + kk][1];
            a0 += h0 * wrd; a1 += h1 * wrd;
            a2 += h0 * wzd; a3 += h1 * wzd;
            a4 += h0 * wnd; a5 += h1 * wnd;
        }
        red[kq][0][f] = a0; red[kq][1][f] = a1;
        red[kq][2][f] = a2; red[kq][3][f] = a3;
        red[kq][4][f] = a4; red[kq][5][f] = a5;
        __syncthreads();

        if (act) {
            // sum K-quarters ascending-k; gate eval for batch bg, feature f
            double ar = 0, az = 0, an = 0;
            #pragma unroll
            for (int qq = 0; qq < 4; ++qq) {
                ar += red[qq][0 * 2 + bq][f];
                az += red[qq][1 * 2 + bq][f];
                an += red[qq][2 * 2 + bq][f];
            }
            double hp = hs[f][bq];
            double rg = 1.0 / (1.0 + exp(-(xr + ar + br)));
            double zg = 1.0 / (1.0 + exp(-(xz + az + bz)));
            double ng = tanh(xn_ + rg * (an + bn));
            double hn = (1.0 - zg) * ng + zg * hp;
            hs[f][bq] = hn;
            hob[(size_t)t * HID] = hn;
        }
        __syncthreads();
    }
}

// ---------------------------------------------------------------------------
// WQ[g][h] = sum_o attn_in_w[g][o] * proj[o][h]   (768x256 f32)
__global__ __launch_bounds__(256) void k_wq(
        const float* __restrict__ aiw, const float* __restrict__ proj,
        float* __restrict__ WQ)
{
    __shared__ float arow[HID];
    int g = blockIdx.x, h = threadIdx.x;
    arow[h] = aiw[(size_t)g * HID + h];
    __syncthreads();
    double acc = 0.0;
    for (int o = 0; o < HID; ++o) acc += (double)arow[o] * (double)proj[(size_t)o * HID + h];
    WQ[(size_t)g * HID + h] = (float)acc;
}

// M[h][k][d] = sum_m wo[m][h*64+d] * w1[k][m]   (4x256x64 f32)
__global__ __launch_bounds__(256) void k_m(
        const float* __restrict__ wo, const float* __restrict__ w1,
        float* __restrict__ M)
{
    __shared__ float w1row[HID];
    int k = blockIdx.x, hd = threadIdx.x;
    w1row[hd] = w1[(size_t)k * HID + hd];
    __syncthreads();
    double acc = 0.0;
    for (int m = 0; m < HID; ++m) acc += (double)w1row[m] * (double)wo[(size_t)m * HID + hd];
    M[(((size_t)(hd >> 6)) * HID + k) * HD + (hd & 63)] = (float)acc;
}

// c[k] = sum_m attn_out_b[m]*mlp_w1[k,m] + mlp_b1[k]
__global__ void k_const(const float* __restrict__ ob, const float* __restrict__ w1,
                        const float* __restrict__ b1, double* __restrict__ c)
{
    int k = threadIdx.x;
    double acc = 0.0;
    for (int m = 0; m < HID; ++m) acc += (double)ob[m] * (double)w1[k * HID + m];
    c[k] = acc + (double)b1[k];
}

// ---------------------------------------------------------------------------
// Pairs: block per (b,i); wave per j (stride 4). Compacted rows offs[b]+n.
__global__ __launch_bounds__(256) void k_pairs3(
        const float* __restrict__ QKV, const float* __restrict__ G,
        const double* __restrict__ c,
        const int* __restrict__ nn, const int* __restrict__ offs,
        const float* __restrict__ gum,
        const float* __restrict__ w2, const float* __restrict__ b2,
        float* __restrict__ adj)
{
    const int bi = blockIdx.x;
    const int b = bi / (NMAX - 1);
    const int i = bi % (NMAX - 1);
    const int nnb = nn[b];
    if (i >= nnb - 1) return;
    const int tid = threadIdx.x;
    const int lane = tid & 63;
    const int wave = tid >> 6;
    const int ofb = offs[b];
    const size_t rowi = (size_t)(ofb + i);

    double cw[4], w2r[4];
    float gir[4][4];
    #pragma unroll
    for (int q = 0; q < 4; ++q) {
        int k = lane + 64 * q;
        cw[q] = c[k];
        w2r[q] = (double)w2[k] - (double)w2[HID + k];
        #pragma unroll
        for (int h = 0; h < 4; ++h) gir[q][h] = G[rowi * 1024 + h * HID + k];
    }
    const int sh = lane >> 4, sd = (lane & 15) * 4;
    const float4 qv  = *(const float4*)&QKV[rowi * GDIM + sh * HD + sd];
    const float4 kv0 = *(const float4*)&QKV[rowi * GDIM + HID + sh * HD + sd];
    double s0 = (double)qv.x * kv0.x + (double)qv.y * kv0.y
              + (double)qv.z * kv0.z + (double)qv.w * kv0.w;
    #pragma unroll
    for (int m = 1; m < 16; m <<= 1) s0 += __shfl_xor(s0, m, 64);
    s0 *= 0.125;
    const double b2d = (double)b2[0] - (double)b2[1];

    for (int j = i + 1 + wave; j < nnb; j += 4) {
        const size_t rowj = (size_t)(ofb + j);
        const float4 kv = *(const float4*)&QKV[rowj * GDIM + HID + sh * HD + sd];
        double s1 = (double)qv.x * kv.x + (double)qv.y * kv.y
                  + (double)qv.z * kv.z + (double)qv.w * kv.w;
        #pragma unroll
        for (int m = 1; m < 16; m <<= 1) s1 += __shfl_xor(s1, m, 64);
        s1 *= 0.125;
        double mx = fmax(s0, s1);
        double e0 = exp(s0 - mx), e1 = exp(s1 - mx);
        double inv = 1.0 / (e0 + e1);
        double a0 = e0 * inv, a1 = e1 * inv;
        double a0h[4], a1h[4];
        #pragma unroll
        for (int h = 0; h < 4; ++h) {
            a0h[h] = __shfl(a0, h * 16, 64);
            a1h[h] = __shfl(a1, h * 16, 64);
        }
        double dsum = 0.0;
        #pragma unroll
        for (int q = 0; q < 4; ++q) {
            int k = lane + 64 * q;
            double pre = cw[q];
            #pragma unroll
            for (int h = 0; h < 4; ++h)
                pre += a0h[h] * (double)gir[q][h]
                     + a1h[h] * (double)G[rowj * 1024 + h * HID + k];
            if (pre > 0.0) dsum += pre * w2r[q];
        }
        #pragma unroll
        for (int m = 1; m < 64; m <<= 1) dsum += __shfl_xor(dsum, m, 64);
        if (lane == 0) {
            int p_idx = i * (2 * NMAX - i - 1) / 2 + (j - i - 1);
            const float* gp = gum + ((size_t)b * NPAIRS + p_idx) * 2;
            double d = dsum + b2d + (double)gp[0] - (double)gp[1];
            if (d >= 0.0) {
                adj[(size_t)b * NMAX * NMAX + i * NMAX + j] = 1.0f;
                adj[(size_t)b * NMAX * NMAX + j * NMAX + i] = 1.0f;
            }
        }
    }
}

__global__ void k_ws_too_small(float* adj) { adj[0] = 2.0f; }

// ---------------------------------------------------------------------------
extern "C" void kernel_launch(void* const* d_in, const int* in_sizes, int n_in,
                              void* d_out, int out_size, void* d_ws, size_t ws_size,
                              hipStream_t stream)
{
    const float* z          = (const float*)d_in[0];
    const int*   nn         = (const int*)d_in[1];
    const float* pos        = (const float*)d_in[3];
    const float* w_ih0      = (const float*)d_in[4];
    const float* w_hh0      = (const float*)d_in[5];
    const float* b_ih0      = (const float*)d_in[6];
    const float* b_hh0      = (const float*)d_in[7];
    const float* w_ih1      = (const float*)d_in[8];
    const float* w_hh1      = (const float*)d_in[9];
    const float* b_ih1      = (const float*)d_in[10];
    const float* b_hh1      = (const float*)d_in[11];
    const float* proj       = (const float*)d_in[12];
    const float* attn_in_w  = (const float*)d_in[13];
    const float* attn_in_b  = (const float*)d_in[14];
    const float* attn_out_w = (const float*)d_in[15];
    const float* attn_out_b = (const float*)d_in[16];
    const float* mlp_w1     = (const float*)d_in[17];
    const float* mlp_b1     = (const float*)d_in[18];
    const float* mlp_w2     = (const float*)d_in[19];
    const float* mlp_b2     = (const float*)d_in[20];
    const float* gum        = (const float*)d_in[21];

    float* adj = (float*)d_out;
    hipMemsetAsync(adj, 0, (size_t)out_size * sizeof(float), stream);

    // Compacted region map — NO live-data aliasing:
    //  offs  @0     (2052 B) | perm @4096 (2048 B)
    //  xg    @8192        157286400  | post-GRU1 overlay: qkv f32 @8192,
    //                                  G f32 @78651392
    //  h0/h1 @157294592   52428800
    //  wRZ0  @209723392   524288 | wN0 @210247680 262144
    //  wRZ1  @210509824   524288 | wN1 @211034112 262144
    //  WQ    @211296256   786432 | M @212082688 262144 | cbf @212344832 2048
    //  Az    @212346880   3145728 | Ap @215492608 307200  (ends 215799808)
    const size_t NEED = 215799808;
    if (ws_size < NEED) { hipLaunchKernelGGL(k_ws_too_small, dim3(1), dim3(1), 0, stream, adj); return; }

    char* ws = (char*)d_ws;
    int*    offs = (int*)(ws);
    int*    perm = (int*)(ws + 4096);
    double* xg   = (double*)(ws + 8192);
    double* h01  = (double*)(ws + 157294592);
    float2* wRZ0 = (float2*)(ws + 209723392);
    float*  wN0  = (float*)(ws + 210247680);
    float2* wRZ1 = (float2*)(ws + 210509824);
    float*  wN1  = (float*)(ws + 211034112);
    float*  WQ   = (float*)(ws + 211296256);
    float*  M    = (float*)(ws + 212082688);
    double* cbf  = (double*)(ws + 212344832);
    double* Az   = (double*)(ws + 212346880);
    double* Ap   = (double*)(ws + 215492608);
    float*  qkv  = (float*)(ws + 8192);
    float*  G    = (float*)(ws + 78651392);
    const int* nlivep = offs + 512;

    // 0) prefix-sum of nn -> offs; nn-sorted pairing -> perm
    hipLaunchKernelGGL(k_offs, dim3(1), dim3(512), 0, stream, nn, offs);
    hipLaunchKernelGGL(k_sort, dim3(1), dim3(512), 0, stream, nn, perm);
    // 1) separable layer-0 input gates: Az = z@w_ih0^T (512x768), Ap = pos@w_ih0^T
    hipLaunchKernelGGL((k_gemm5<LATENT, false, true, false, false>), dim3(8, 6), dim3(256), 0, stream,
                       (const void*)z, (long)LATENT, 0, nullptr,
                       w_ih0, LATENT, 0L, (const float*)nullptr,
                       (void*)Az, (long)GDIM, 0);
    hipLaunchKernelGGL(k_ap, dim3(NMAX), dim3(256), 0, stream, pos, w_ih0, Ap);
    // 2) GRU layer 0 (sorted pairing, early-freeze, compacted h0)
    hipLaunchKernelGGL(k_pack_bat, dim3(256), dim3(256), 0, stream, w_hh0, wRZ0, wN0);
    hipLaunchKernelGGL((k_gru8<1>), dim3(256), dim3(1024), 0, stream,
                       Az, Ap, b_ih0, nn, offs, perm, h01, wRZ0, wN0, b_hh0);
    // 3) layer-1 input gates over compacted live rows only
    hipLaunchKernelGGL((k_gemm5<HID, true, true, true, true>), dim3(400, 6), dim3(256), 0, stream,
                       (const void*)h01, (long)HID, 0, nlivep,
                       w_ih1, HID, 0L, b_ih1, (void*)xg, (long)GDIM, 0);
    // 4) GRU layer 1 (h1 overwrites dead h0; reads compacted xg)
    hipLaunchKernelGGL(k_pack_bat, dim3(256), dim3(256), 0, stream, w_hh1, wRZ1, wN1);
    hipLaunchKernelGGL((k_gru8<0>), dim3(256), dim3(1024), 0, stream,
                       xg, nullptr, nullptr, nn, offs, perm, h01, wRZ1, wN1, b_hh1);
    // 5) fused (proj @ attn_in_w), then qkv from compacted h1 (all rows live)
    hipLaunchKernelGGL(k_wq, dim3(768), dim3(256), 0, stream, attn_in_w, proj, WQ);
    hipLaunchKernelGGL((k_gemm5<HID, true, false, true, true>), dim3(400, 6), dim3(256), 0, stream,
                       (const void*)h01, (long)HID, 0, nlivep,
                       WQ, HID, 0L, attn_in_b, (void*)qkv, (long)GDIM, 0);
    // 6) M precompute + single fused G GEMM (grid.z = head, compacted rows)
    hipLaunchKernelGGL(k_m, dim3(256), dim3(256), 0, stream, attn_out_w, mlp_w1, M);
    hipLaunchKernelGGL(k_const, dim3(1), dim3(256), 0, stream, attn_out_b, mlp_w1, mlp_b1, cbf);
    hipLaunchKernelGGL((k_gemm5<HD, false, false, false, true>), dim3(400, 2, 4), dim3(256), 0, stream,
                       (const void*)(qkv + 2 * HID), (long)GDIM, HD, nlivep,
                       M, HD, (long)(HID * HD), (const float*)nullptr,
                       (void*)G, 1024L, HID);
    // 7) pairs (compacted row indexing)
    hipLaunchKernelGGL(k_pairs3, dim3(BB * (NMAX - 1)), dim3(256), 0, stream,
                       qkv, G, cbf, nn, offs, gum, mlp_w2, mlp_b2, adj);
}

// Round 18
// 1618.958 us; speedup vs baseline: 1.4995x; 1.1101x over previous
//
#include <hip/hip_runtime.h>
#include <hip/hip_bf16.h>
#include <math.h>

#define BB 512
#define LATENT 128
#define HID 256
#define GDIM 768
#define NMAX 50
#define NHEADS 4
#define HD 64
#define NPAIRS 1225

// ---------------------------------------------------------------------------
// offs[b] = exclusive prefix sum of nn; offs[512] = total live rows (Nlive)
__global__ __launch_bounds__(512) void k_offs(const int* __restrict__ nn,
                                              int* __restrict__ offs)
{
    __shared__ int s[512];
    const int tid = threadIdx.x;
    s[tid] = nn[tid];
    __syncthreads();
    for (int d = 1; d < 512; d <<= 1) {
        int v = (tid >= d) ? s[tid - d] : 0;
        __syncthreads();
        s[tid] += v;
        __syncthreads();
    }
    if (tid == 0) offs[0] = 0;
    offs[tid + 1] = s[tid];
}

// ---------------------------------------------------------------------------
// Bitonic sort of 512 batches by (nn, idx) ascending -> perm.
__global__ __launch_bounds__(512) void k_sort(const int* __restrict__ nn,
                                              int* __restrict__ perm)
{
    __shared__ int s[512];
    const int tid = threadIdx.x;
    s[tid] = nn[tid] * 1024 + tid;       // composite key, fully deterministic
    __syncthreads();
    for (int k = 2; k <= 512; k <<= 1) {
        for (int j = k >> 1; j > 0; j >>= 1) {
            int ixj = tid ^ j;
            if (ixj > tid) {
                int a = s[tid], b = s[ixj];
                bool up = (tid & k) == 0;
                if (up ? (a > b) : (a < b)) { s[tid] = b; s[ixj] = a; }
            }
            __syncthreads();
        }
    }
    perm[tid] = s[tid] & 1023;
}

// ---------------------------------------------------------------------------
// Tiled GEMM, double-buffered LDS: O[r][oc] = sum_k X[r][k]*W[oc][k] (+bias)
// Block tile 64x128, 256 threads, thread tile 4x8, f64 accumulate.
// Rows are COMPACTED live rows; NLIVE => early-exit blocks beyond *nlivep.
template<int KD, bool XF64, bool OF64, bool BIAS, bool NLIVE>
__global__ __launch_bounds__(256) void k_gemm5(
        const void* __restrict__ Xv, long xstride, int xzoff,
        const int* __restrict__ nlivep,
        const float* __restrict__ W, int wstride, long wzoff,
        const float* __restrict__ bias,
        void* __restrict__ Ov, long ostride, int ozoff)
{
    const int rb = blockIdx.x * 64;
    if (NLIVE) { if (rb >= *nlivep) return; }
    __shared__ double xs[2][64][17];
    __shared__ float  wsm[2][128][17];
    const int ob = blockIdx.y * 128;
    const int zid = blockIdx.z;
    const int tid = threadIdx.x;
    const int ty = tid >> 4, tx = tid & 15;
    const int lr  = tid >> 2;            // X tile row 0..63
    const int lk  = (tid & 3) * 4;       // X k offset 0,4,8,12
    const int lr2 = tid >> 1;            // W tile row 0..127
    const int lk2 = (tid & 1) * 8;       // W k offset 0/8
    const int xrow = rb + lr;

    const double* xp64 = nullptr; const float* xp32 = nullptr;
    if (XF64) xp64 = (const double*)Xv + (size_t)xrow * xstride + zid * (long)xzoff;
    else      xp32 = (const float*)Xv + (size_t)xrow * xstride + zid * (long)xzoff;
    const float* wp = W + (size_t)zid * wzoff + (size_t)(ob + lr2) * wstride + lk2;

    double xstg[4]; float wstg[8];

#define GEMM_LOAD(K0)                                                          \
    {                                                                          \
        if (XF64) {                                                            \
            _Pragma("unroll")                                                  \
            for (int u = 0; u < 4; ++u) xstg[u] = xp64[(K0) + lk + u];         \
        } else {                                                               \
            _Pragma("unroll")                                                  \
            for (int u = 0; u < 4; ++u) xstg[u] = (double)xp32[(K0) + lk + u]; \
        }                                                                      \
        _Pragma("unroll")                                                      \
        for (int u = 0; u < 8; ++u) wstg[u] = wp[(K0) + u];                    \
    }

#define GEMM_WRITE(BUF)                                                        \
    {                                                                          \
        _Pragma("unroll")                                                      \
        for (int u = 0; u < 4; ++u) xs[(BUF)][lr][lk + u] = xstg[u];           \
        _Pragma("unroll")                                                      \
        for (int u = 0; u < 8; ++u) wsm[(BUF)][lr2][lk2 + u] = wstg[u];        \
    }

    double acc[4][8];
    #pragma unroll
    for (int i = 0; i < 4; ++i)
        #pragma unroll
        for (int j = 0; j < 8; ++j) acc[i][j] = 0.0;

    constexpr int NC = KD / 16;
    GEMM_LOAD(0);
    GEMM_WRITE(0);
    for (int c = 0; c < NC; ++c) {
        __syncthreads();
        if (c + 1 < NC) GEMM_LOAD((c + 1) * 16);
        const int bi = c & 1;
        #pragma unroll
        for (int kk = 0; kk < 16; ++kk) {
            double wv[8];
            #pragma unroll
            for (int j = 0; j < 8; ++j) wv[j] = (double)wsm[bi][j * 16 + tx][kk];
            #pragma unroll
            for (int i = 0; i < 4; ++i) {
                double xr = xs[bi][ty * 4 + i][kk];
                #pragma unroll
                for (int j = 0; j < 8; ++j) acc[i][j] += xr * wv[j];
            }
        }
        if (c + 1 < NC) GEMM_WRITE((c + 1) & 1);
    }
    #pragma unroll
    for (int i = 0; i < 4; ++i) {
        size_t row = rb + ty * 4 + i;
        #pragma unroll
        for (int j = 0; j < 8; ++j) {
            int ocg = ob + j * 16 + tx;
            double v = acc[i][j];
            if (BIAS) v += (double)bias[ocg];
            size_t o = row * ostride + (size_t)zid * ozoff + ocg;
            if (OF64) ((double*)Ov)[o] = v;
            else      ((float*)Ov)[o] = (float)v;
        }
    }
#undef GEMM_LOAD
#undef GEMM_WRITE
}

// ---------------------------------------------------------------------------
// Ap[t][g] = sum_i pos[t][i] * w_ih0[g][i]   (50 x 768, f64, no bias)
__global__ __launch_bounds__(256) void k_ap(
        const float* __restrict__ pos, const float* __restrict__ w,
        double* __restrict__ Ap)
{
    __shared__ float ps[LATENT];
    const int t = blockIdx.x;
    const int tid = threadIdx.x;
    if (tid < LATENT) ps[tid] = pos[(size_t)t * LATENT + tid];
    __syncthreads();
    for (int g = tid; g < GDIM; g += 256) {
        double acc = 0.0;
        const float* wr = w + (size_t)g * LATENT;
        for (int i = 0; i < LATENT; ++i) acc += (double)ps[i] * (double)wr[i];
        Ap[(size_t)t * GDIM + g] = acc;
    }
}

// ---------------------------------------------------------------------------
// pack w_hh f32 [768][256] -> k-pair-packed:
//   wRZ4[k2][f] = (r_{2k2}, z_{2k2}, r_{2k2+1}, z_{2k2+1})  float4
//   wN2 [k2][f] = (n_{2k2}, n_{2k2+1})                       float2
// Same bytes as before, HALF the load instructions in the GRU MAC.
__global__ __launch_bounds__(256) void k_pack_v4(
        const float* __restrict__ whh, float4* __restrict__ wRZ4,
        float2* __restrict__ wN2)
{
    int k2 = blockIdx.x, f = threadIdx.x;     // k2 = 0..127
    int k0 = 2 * k2, k1 = 2 * k2 + 1;
    float r0 = whh[(size_t)(0 * HID + f) * HID + k0];
    float z0 = whh[(size_t)(1 * HID + f) * HID + k0];
    float n0 = whh[(size_t)(2 * HID + f) * HID + k0];
    float r1 = whh[(size_t)(0 * HID + f) * HID + k1];
    float z1 = whh[(size_t)(1 * HID + f) * HID + k1];
    float n1 = whh[(size_t)(2 * HID + f) * HID + k1];
    wRZ4[(size_t)k2 * HID + f] = make_float4(r0, z0, r1, z1);
    wN2[(size_t)k2 * HID + f]  = make_float2(n0, n1);
}

// ---------------------------------------------------------------------------
// Persistent batch-sliced GRU (R13/R17-proven body): grid 256 x 1024, BG=2,
// kq-split K, early-freeze to tmax, compacted h at rows offs[bg]+t,
// nn-sorted batch pairing via perm.
// R18: k-pair-packed weights (float4+float2 per 2 k) — half the load
// instructions, same bytes, same ascending-k accumulation order =>
// bitwise-identical live h.
// XGMODE 0: x-gates from compacted xg rows. XGMODE 1: Az+Ap+b_ih.
template<int XGMODE>
__global__ __launch_bounds__(1024) void k_gru8(
        const double* __restrict__ xg,            // XGMODE0: xg; XGMODE1: Az
        const double* __restrict__ Ap,
        const float* __restrict__ bih,
        const int* __restrict__ nn,
        const int* __restrict__ offs,
        const int* __restrict__ perm,
        double* __restrict__ hout,
        const float4* __restrict__ wRZ4, const float2* __restrict__ wN2,
        const float* __restrict__ bhh)
{
    const int tid = threadIdx.x;
    const int f  = tid & 255;
    const int kq = tid >> 8;             // 0..3
    const int bA = perm[2 * blockIdx.x];
    const int bB = perm[2 * blockIdx.x + 1];

    __shared__ double hs[HID][2];        // 4 KB
    __shared__ double red[4][6][HID];    // 48 KB: [kq][gate*2+b][f]

    if (kq < 2) hs[f][kq] = 0.0;

    const int nn0 = nn[bA], nn1 = nn[bB];
    const int tmax = nn0 > nn1 ? nn0 : nn1;

    const int bq = kq;                   // batch slot for gate phase
    const int bg = (kq == 1) ? bB : bA;  // kq0 -> bA, kq1 -> bB (kq>=2 unused)
    const int nnb = (kq == 0) ? nn0 : ((kq == 1) ? nn1 : 0);
    const int offs_bg = offs[bg];
    double br = 0, bz = 0, bn = 0, bihr = 0, bihz = 0, bihn = 0;
    if (kq < 2) {
        br = (double)bhh[f]; bz = (double)bhh[HID + f]; bn = (double)bhh[2 * HID + f];
        if (XGMODE == 1) {
            bihr = (double)bih[f]; bihz = (double)bih[HID + f]; bihn = (double)bih[2 * HID + f];
        }
    }
    const float4* wrz4 = wRZ4 + (size_t)(kq * 32) * HID + f;   // 32 k-pairs/quarter
    const float2* wn2  = wN2  + (size_t)(kq * 32) * HID + f;
    const double* xbase = (XGMODE == 1)
        ? xg + (size_t)bg * GDIM + f
        : xg + (size_t)offs_bg * GDIM + f;
    double* hob = hout + (size_t)offs_bg * HID + f;
    const int kbase = kq * 64;

    __syncthreads();

    for (int t = 0; t < tmax; ++t) {
        const bool act = (kq < 2) && (t < nnb);
        // x-gate values for (bg, f), active threads only, issued early
        double xr = 0, xz = 0, xn_ = 0;
        if (act) {
            if (XGMODE == 0) {
                const double* x = xbase + (size_t)t * GDIM;
                xr = x[0]; xz = x[HID]; xn_ = x[2 * HID];
            } else {
                const double* ap = Ap + (size_t)t * GDIM + f;
                xr  = xbase[0]       + ap[0]       + bihr;
                xz  = xbase[HID]     + ap[HID]     + bihz;
                xn_ = xbase[2 * HID] + ap[2 * HID] + bihn;
            }
        }

        // MAC: K-quarter kq, both batches, 2 k per iteration (ascending k)
        double a0 = 0, a1 = 0, a2 = 0, a3 = 0, a4 = 0, a5 = 0;
        #pragma unroll 8
        for (int kk2 = 0; kk2 < 32; ++kk2) {
            float4 rz = wrz4[(size_t)kk2 * HID];
            float2 nw = wn2[(size_t)kk2 * HID];
            const int k = kbase + 2 * kk2;
            double h00 = hs[k][0],     h01 = hs[k][1];
            double h10 = hs[k + 1][0], h11 = hs[k + 1][1];
            a0 += h00 * (double)rz.x; a1 += h01 * (double)rz.x;
            a2 += h00 * (double)rz.y; a3 += h01 * (double)rz.y;
            a4 += h00 * (double)nw.x; a5 += h01 * (double)nw.x;
            a0 += h10 * (double)rz.z; a1 += h11 * (double)rz.z;
            a2 += h10 * (double)rz.w; a3 += h11 * (double)rz.w;
            a4 += h10 * (double)nw.y; a5 += h11 * (double)nw.y;
        }
        red[kq][0][f] = a0; red[kq][1][f] = a1;
        red[kq][2][f] = a2; red[kq][3][f] = a3;
        red[kq][4][f] = a4; red[kq][5][f] = a5;
        __syncthreads();

        if (act) {
            // sum K-quarters ascending-k; gate eval for batch bg, feature f
            double ar = 0, az = 0, an = 0;
            #pragma unroll
            for (int qq = 0; qq < 4; ++qq) {
                ar += red[qq][0 * 2 + bq][f];
                az += red[qq][1 * 2 + bq][f];
                an += red[qq][2 * 2 + bq][f];
            }
            double hp = hs[f][bq];
            double rg = 1.0 / (1.0 + exp(-(xr + ar + br)));
            double zg = 1.0 / (1.0 + exp(-(xz + az + bz)));
            double ng = tanh(xn_ + rg * (an + bn));
            double hn = (1.0 - zg) * ng + zg * hp;
            hs[f][bq] = hn;
            hob[(size_t)t * HID] = hn;
        }
        __syncthreads();
    }
}

// ---------------------------------------------------------------------------
// WQ[g][h] = sum_o attn_in_w[g][o] * proj[o][h]   (768x256 f32)
__global__ __launch_bounds__(256) void k_wq(
        const float* __restrict__ aiw, const float* __restrict__ proj,
        float* __restrict__ WQ)
{
    __shared__ float arow[HID];
    int g = blockIdx.x, h = threadIdx.x;
    arow[h] = aiw[(size_t)g * HID + h];
    __syncthreads();
    double acc = 0.0;
    for (int o = 0; o < HID; ++o) acc += (double)arow[o] * (double)proj[(size_t)o * HID + h];
    WQ[(size_t)g * HID + h] = (float)acc;
}

// M[h][k][d] = sum_m wo[m][h*64+d] * w1[k][m]   (4x256x64 f32)
__global__ __launch_bounds__(256) void k_m(
        const float* __restrict__ wo, const float* __restrict__ w1,
        float* __restrict__ M)
{
    __shared__ float w1row[HID];
    int k = blockIdx.x, hd = threadIdx.x;
    w1row[hd] = w1[(size_t)k * HID + hd];
    __syncthreads();
    double acc = 0.0;
    for (int m = 0; m < HID; ++m) acc += (double)w1row[m] * (double)wo[(size_t)m * HID + hd];
    M[(((size_t)(hd >> 6)) * HID + k) * HD + (hd & 63)] = (float)acc;
}

// c[k] = sum_m attn_out_b[m]*mlp_w1[k,m] + mlp_b1[k]
__global__ void k_const(const float* __restrict__ ob, const float* __restrict__ w1,
                        const float* __restrict__ b1, double* __restrict__ c)
{
    int k = threadIdx.x;
    double acc = 0.0;
    for (int m = 0; m < HID; ++m) acc += (double)ob[m] * (double)w1[k * HID + m];
    c[k] = acc + (double)b1[k];
}

// ---------------------------------------------------------------------------
// Pairs: block per (b,i); wave per j (stride 4). Compacted rows offs[b]+n.
__global__ __launch_bounds__(256) void k_pairs3(
        const float* __restrict__ QKV, const float* __restrict__ G,
        const double* __restrict__ c,
        const int* __restrict__ nn, const int* __restrict__ offs,
        const float* __restrict__ gum,
        const float* __restrict__ w2, const float* __restrict__ b2,
        float* __restrict__ adj)
{
    const int bi = blockIdx.x;
    const int b = bi / (NMAX - 1);
    const int i = bi % (NMAX - 1);
    const int nnb = nn[b];
    if (i >= nnb - 1) return;
    const int tid = threadIdx.x;
    const int lane = tid & 63;
    const int wave = tid >> 6;
    const int ofb = offs[b];
    const size_t rowi = (size_t)(ofb + i);

    double cw[4], w2r[4];
    float gir[4][4];
    #pragma unroll
    for (int q = 0; q < 4; ++q) {
        int k = lane + 64 * q;
        cw[q] = c[k];
        w2r[q] = (double)w2[k] - (double)w2[HID + k];
        #pragma unroll
        for (int h = 0; h < 4; ++h) gir[q][h] = G[rowi * 1024 + h * HID + k];
    }
    const int sh = lane >> 4, sd = (lane & 15) * 4;
    const float4 qv  = *(const float4*)&QKV[rowi * GDIM + sh * HD + sd];
    const float4 kv0 = *(const float4*)&QKV[rowi * GDIM + HID + sh * HD + sd];
    double s0 = (double)qv.x * kv0.x + (double)qv.y * kv0.y
              + (double)qv.z * kv0.z + (double)qv.w * kv0.w;
    #pragma unroll
    for (int m = 1; m < 16; m <<= 1) s0 += __shfl_xor(s0, m, 64);
    s0 *= 0.125;
    const double b2d = (double)b2[0] - (double)b2[1];

    for (int j = i + 1 + wave; j < nnb; j += 4) {
        const size_t rowj = (size_t)(ofb + j);
        const float4 kv = *(const float4*)&QKV[rowj * GDIM + HID + sh * HD + sd];
        double s1 = (double)qv.x * kv.x + (double)qv.y * kv.y
                  + (double)qv.z * kv.z + (double)qv.w * kv.w;
        #pragma unroll
        for (int m = 1; m < 16; m <<= 1) s1 += __shfl_xor(s1, m, 64);
        s1 *= 0.125;
        double mx = fmax(s0, s1);
        double e0 = exp(s0 - mx), e1 = exp(s1 - mx);
        double inv = 1.0 / (e0 + e1);
        double a0 = e0 * inv, a1 = e1 * inv;
        double a0h[4], a1h[4];
        #pragma unroll
        for (int h = 0; h < 4; ++h) {
            a0h[h] = __shfl(a0, h * 16, 64);
            a1h[h] = __shfl(a1, h * 16, 64);
        }
        double dsum = 0.0;
        #pragma unroll
        for (int q = 0; q < 4; ++q) {
            int k = lane + 64 * q;
            double pre = cw[q];
            #pragma unroll
            for (int h = 0; h < 4; ++h)
                pre += a0h[h] * (double)gir[q][h]
                     + a1h[h] * (double)G[rowj * 1024 + h * HID + k];
            if (pre > 0.0) dsum += pre * w2r[q];
        }
        #pragma unroll
        for (int m = 1; m < 64; m <<= 1) dsum += __shfl_xor(dsum, m, 64);
        if (lane == 0) {
            int p_idx = i * (2 * NMAX - i - 1) / 2 + (j - i - 1);
            const float* gp = gum + ((size_t)b * NPAIRS + p_idx) * 2;
            double d = dsum + b2d + (double)gp[0] - (double)gp[1];
            if (d >= 0.0) {
                adj[(size_t)b * NMAX * NMAX + i * NMAX + j] = 1.0f;
                adj[(size_t)b * NMAX * NMAX + j * NMAX + i] = 1.0f;
            }
        }
    }
}

__global__ void k_ws_too_small(float* adj) { adj[0] = 2.0f; }

// ---------------------------------------------------------------------------
extern "C" void kernel_launch(void* const* d_in, const int* in_sizes, int n_in,
                              void* d_out, int out_size, void* d_ws, size_t ws_size,
                              hipStream_t stream)
{
    const float* z          = (const float*)d_in[0];
    const int*   nn         = (const int*)d_in[1];
    const float* pos        = (const float*)d_in[3];
    const float* w_ih0      = (const float*)d_in[4];
    const float* w_hh0      = (const float*)d_in[5];
    const float* b_ih0      = (const float*)d_in[6];
    const float* b_hh0      = (const float*)d_in[7];
    const float* w_ih1      = (const float*)d_in[8];
    const float* w_hh1      = (const float*)d_in[9];
    const float* b_ih1      = (const float*)d_in[10];
    const float* b_hh1      = (const float*)d_in[11];
    const float* proj       = (const float*)d_in[12];
    const float* attn_in_w  = (const float*)d_in[13];
    const float* attn_in_b  = (const float*)d_in[14];
    const float* attn_out_w = (const float*)d_in[15];
    const float* attn_out_b = (const float*)d_in[16];
    const float* mlp_w1     = (const float*)d_in[17];
    const float* mlp_b1     = (const float*)d_in[18];
    const float* mlp_w2     = (const float*)d_in[19];
    const float* mlp_b2     = (const float*)d_in[20];
    const float* gum        = (const float*)d_in[21];

    float* adj = (float*)d_out;
    hipMemsetAsync(adj, 0, (size_t)out_size * sizeof(float), stream);

    // Compacted region map — NO live-data aliasing:
    //  offs  @0     (2052 B) | perm @4096 (2048 B)
    //  xg    @8192        157286400  | post-GRU1 overlay: qkv f32 @8192,
    //                                  G f32 @78651392
    //  h0/h1 @157294592   52428800
    //  wRZ40 @209723392   524288 | wN20 @210247680 262144
    //  wRZ41 @210509824   524288 | wN21 @211034112 262144
    //  WQ    @211296256   786432 | M @212082688 262144 | cbf @212344832 2048
    //  Az    @212346880   3145728 | Ap @215492608 307200  (ends 215799808)
    const size_t NEED = 215799808;
    if (ws_size < NEED) { hipLaunchKernelGGL(k_ws_too_small, dim3(1), dim3(1), 0, stream, adj); return; }

    char* ws = (char*)d_ws;
    int*    offs  = (int*)(ws);
    int*    perm  = (int*)(ws + 4096);
    double* xg    = (double*)(ws + 8192);
    double* h01   = (double*)(ws + 157294592);
    float4* wRZ40 = (float4*)(ws + 209723392);
    float2* wN20  = (float2*)(ws + 210247680);
    float4* wRZ41 = (float4*)(ws + 210509824);
    float2* wN21  = (float2*)(ws + 211034112);
    float*  WQ    = (float*)(ws + 211296256);
    float*  M     = (float*)(ws + 212082688);
    double* cbf   = (double*)(ws + 212344832);
    double* Az    = (double*)(ws + 212346880);
    double* Ap    = (double*)(ws + 215492608);
    float*  qkv   = (float*)(ws + 8192);
    float*  G     = (float*)(ws + 78651392);
    const int* nlivep = offs + 512;

    // 0) prefix-sum of nn -> offs; nn-sorted pairing -> perm
    hipLaunchKernelGGL(k_offs, dim3(1), dim3(512), 0, stream, nn, offs);
    hipLaunchKernelGGL(k_sort, dim3(1), dim3(512), 0, stream, nn, perm);
    // 1) separable layer-0 input gates: Az = z@w_ih0^T (512x768), Ap = pos@w_ih0^T
    hipLaunchKernelGGL((k_gemm5<LATENT, false, true, false, false>), dim3(8, 6), dim3(256), 0, stream,
                       (const void*)z, (long)LATENT, 0, nullptr,
                       w_ih0, LATENT, 0L, (const float*)nullptr,
                       (void*)Az, (long)GDIM, 0);
    hipLaunchKernelGGL(k_ap, dim3(NMAX), dim3(256), 0, stream, pos, w_ih0, Ap);
    // 2) GRU layer 0 (k-pair-packed weights, sorted pairing, early-freeze)
    hipLaunchKernelGGL(k_pack_v4, dim3(128), dim3(256), 0, stream, w_hh0, wRZ40, wN20);
    hipLaunchKernelGGL((k_gru8<1>), dim3(256), dim3(1024), 0, stream,
                       Az, Ap, b_ih0, nn, offs, perm, h01, wRZ40, wN20, b_hh0);
    // 3) layer-1 input gates over compacted live rows only
    hipLaunchKernelGGL((k_gemm5<HID, true, true, true, true>), dim3(400, 6), dim3(256), 0, stream,
                       (const void*)h01, (long)HID, 0, nlivep,
                       w_ih1, HID, 0L, b_ih1, (void*)xg, (long)GDIM, 0);
    // 4) GRU layer 1 (h1 overwrites dead h0; reads compacted xg)
    hipLaunchKernelGGL(k_pack_v4, dim3(128), dim3(256), 0, stream, w_hh1, wRZ41, wN21);
    hipLaunchKernelGGL((k_gru8<0>), dim3(256), dim3(1024), 0, stream,
                       xg, nullptr, nullptr, nn, offs, perm, h01, wRZ41, wN21, b_hh1);
    // 5) fused (proj @ attn_in_w), then qkv from compacted h1 (all rows live)
    hipLaunchKernelGGL(k_wq, dim3(768), dim3(256), 0, stream, attn_in_w, proj, WQ);
    hipLaunchKernelGGL((k_gemm5<HID, true, false, true, true>), dim3(400, 6), dim3(256), 0, stream,
                       (const void*)h01, (long)HID, 0, nlivep,
                       WQ, HID, 0L, attn_in_b, (void*)qkv, (long)GDIM, 0);
    // 6) M precompute + single fused G GEMM (grid.z = head, compacted rows)
    hipLaunchKernelGGL(k_m, dim3(256), dim3(256), 0, stream, attn_out_w, mlp_w1, M);
    hipLaunchKernelGGL(k_const, dim3(1), dim3(256), 0, stream, attn_out_b, mlp_w1, mlp_b1, cbf);
    hipLaunchKernelGGL((k_gemm5<HD, false, false, false, true>), dim3(400, 2, 4), dim3(256), 0, stream,
                       (const void*)(qkv + 2 * HID), (long)GDIM, HD, nlivep,
                       M, HD, (long)(HID * HD), (const float*)nullptr,
                       (void*)G, 1024L, HID);
    // 7) pairs (compacted row indexing)
    hipLaunchKernelGGL(k_pairs3, dim3(BB * (NMAX - 1)), dim3(256), 0, stream,
                       qkv, G, cbf, nn, offs, gum, mlp_w2, mlp_b2, adj);
}

// Round 19
// 1617.823 us; speedup vs baseline: 1.5006x; 1.0007x over previous
//
#include <hip/hip_runtime.h>
#include <hip/hip_bf16.h>
#include <math.h>

#define BB 512
#define LATENT 128
#define HID 256
#define GDIM 768
#define NMAX 50
#define NHEADS 4
#define HD 64
#define NPAIRS 1225

// ---------------------------------------------------------------------------
// offs[b] = exclusive prefix sum of nn; offs[512] = total live rows (Nlive)
__global__ __launch_bounds__(512) void k_offs(const int* __restrict__ nn,
                                              int* __restrict__ offs)
{
    __shared__ int s[512];
    const int tid = threadIdx.x;
    s[tid] = nn[tid];
    __syncthreads();
    for (int d = 1; d < 512; d <<= 1) {
        int v = (tid >= d) ? s[tid - d] : 0;
        __syncthreads();
        s[tid] += v;
        __syncthreads();
    }
    if (tid == 0) offs[0] = 0;
    offs[tid + 1] = s[tid];
}

// ---------------------------------------------------------------------------
// Bitonic sort of 512 batches by (nn, idx) ascending -> perm.
__global__ __launch_bounds__(512) void k_sort(const int* __restrict__ nn,
                                              int* __restrict__ perm)
{
    __shared__ int s[512];
    const int tid = threadIdx.x;
    s[tid] = nn[tid] * 1024 + tid;       // composite key, fully deterministic
    __syncthreads();
    for (int k = 2; k <= 512; k <<= 1) {
        for (int j = k >> 1; j > 0; j >>= 1) {
            int ixj = tid ^ j;
            if (ixj > tid) {
                int a = s[tid], b = s[ixj];
                bool up = (tid & k) == 0;
                if (up ? (a > b) : (a < b)) { s[tid] = b; s[ixj] = a; }
            }
            __syncthreads();
        }
    }
    perm[tid] = s[tid] & 1023;
}

// ---------------------------------------------------------------------------
// Tiled GEMM, double-buffered LDS: O[r][oc] = sum_k X[r][k]*W[oc][k] (+bias)
// Block tile 64x128, 256 threads, thread tile 4x8, f64 accumulate.
// Rows are COMPACTED live rows; NLIVE => early-exit blocks beyond *nlivep.
template<int KD, bool XF64, bool OF64, bool BIAS, bool NLIVE>
__global__ __launch_bounds__(256) void k_gemm5(
        const void* __restrict__ Xv, long xstride, int xzoff,
        const int* __restrict__ nlivep,
        const float* __restrict__ W, int wstride, long wzoff,
        const float* __restrict__ bias,
        void* __restrict__ Ov, long ostride, int ozoff)
{
    const int rb = blockIdx.x * 64;
    if (NLIVE) { if (rb >= *nlivep) return; }
    __shared__ double xs[2][64][17];
    __shared__ float  wsm[2][128][17];
    const int ob = blockIdx.y * 128;
    const int zid = blockIdx.z;
    const int tid = threadIdx.x;
    const int ty = tid >> 4, tx = tid & 15;
    const int lr  = tid >> 2;            // X tile row 0..63
    const int lk  = (tid & 3) * 4;       // X k offset 0,4,8,12
    const int lr2 = tid >> 1;            // W tile row 0..127
    const int lk2 = (tid & 1) * 8;       // W k offset 0/8
    const int xrow = rb + lr;

    const double* xp64 = nullptr; const float* xp32 = nullptr;
    if (XF64) xp64 = (const double*)Xv + (size_t)xrow * xstride + zid * (long)xzoff;
    else      xp32 = (const float*)Xv + (size_t)xrow * xstride + zid * (long)xzoff;
    const float* wp = W + (size_t)zid * wzoff + (size_t)(ob + lr2) * wstride + lk2;

    double xstg[4]; float wstg[8];

#define GEMM_LOAD(K0)                                                          \
    {                                                                          \
        if (XF64) {                                                            \
            _Pragma("unroll")                                                  \
            for (int u = 0; u < 4; ++u) xstg[u] = xp64[(K0) + lk + u];         \
        } else {                                                               \
            _Pragma("unroll")                                                  \
            for (int u = 0; u < 4; ++u) xstg[u] = (double)xp32[(K0) + lk + u]; \
        }                                                                      \
        _Pragma("unroll")                                                      \
        for (int u = 0; u < 8; ++u) wstg[u] = wp[(K0) + u];                    \
    }

#define GEMM_WRITE(BUF)                                                        \
    {                                                                          \
        _Pragma("unroll")                                                      \
        for (int u = 0; u < 4; ++u) xs[(BUF)][lr][lk + u] = xstg[u];           \
        _Pragma("unroll")                                                      \
        for (int u = 0; u < 8; ++u) wsm[(BUF)][lr2][lk2 + u] = wstg[u];        \
    }

    double acc[4][8];
    #pragma unroll
    for (int i = 0; i < 4; ++i)
        #pragma unroll
        for (int j = 0; j < 8; ++j) acc[i][j] = 0.0;

    constexpr int NC = KD / 16;
    GEMM_LOAD(0);
    GEMM_WRITE(0);
    for (int c = 0; c < NC; ++c) {
        __syncthreads();
        if (c + 1 < NC) GEMM_LOAD((c + 1) * 16);
        const int bi = c & 1;
        #pragma unroll
        for (int kk = 0; kk < 16; ++kk) {
            double wv[8];
            #pragma unroll
            for (int j = 0; j < 8; ++j) wv[j] = (double)wsm[bi][j * 16 + tx][kk];
            #pragma unroll
            for (int i = 0; i < 4; ++i) {
                double xr = xs[bi][ty * 4 + i][kk];
                #pragma unroll
                for (int j = 0; j < 8; ++j) acc[i][j] += xr * wv[j];
            }
        }
        if (c + 1 < NC) GEMM_WRITE((c + 1) & 1);
    }
    #pragma unroll
    for (int i = 0; i < 4; ++i) {
        size_t row = rb + ty * 4 + i;
        #pragma unroll
        for (int j = 0; j < 8; ++j) {
            int ocg = ob + j * 16 + tx;
            double v = acc[i][j];
            if (BIAS) v += (double)bias[ocg];
            size_t o = row * ostride + (size_t)zid * ozoff + ocg;
            if (OF64) ((double*)Ov)[o] = v;
            else      ((float*)Ov)[o] = (float)v;
        }
    }
#undef GEMM_LOAD
#undef GEMM_WRITE
}

// ---------------------------------------------------------------------------
// Ap[t][g] = sum_i pos[t][i] * w_ih0[g][i]   (50 x 768, f64, no bias)
__global__ __launch_bounds__(256) void k_ap(
        const float* __restrict__ pos, const float* __restrict__ w,
        double* __restrict__ Ap)
{
    __shared__ float ps[LATENT];
    const int t = blockIdx.x;
    const int tid = threadIdx.x;
    if (tid < LATENT) ps[tid] = pos[(size_t)t * LATENT + tid];
    __syncthreads();
    for (int g = tid; g < GDIM; g += 256) {
        double acc = 0.0;
        const float* wr = w + (size_t)g * LATENT;
        for (int i = 0; i < LATENT; ++i) acc += (double)ps[i] * (double)wr[i];
        Ap[(size_t)t * GDIM + g] = acc;
    }
}

// ---------------------------------------------------------------------------
// pack w_hh f32 [768][256] -> k-pair-packed:
//   wRZ4[k2][f] = (r_{2k2}, z_{2k2}, r_{2k2+1}, z_{2k2+1})  float4
//   wN2 [k2][f] = (n_{2k2}, n_{2k2+1})                       float2
// Same bytes as before, HALF the load instructions in the GRU MAC.
__global__ __launch_bounds__(256) void k_pack_v4(
        const float* __restrict__ whh, float4* __restrict__ wRZ4,
        float2* __restrict__ wN2)
{
    int k2 = blockIdx.x, f = threadIdx.x;     // k2 = 0..127
    int k0 = 2 * k2, k1 = 2 * k2 + 1;
    float r0 = whh[(size_t)(0 * HID + f) * HID + k0];
    float z0 = whh[(size_t)(1 * HID + f) * HID + k0];
    float n0 = whh[(size_t)(2 * HID + f) * HID + k0];
    float r1 = whh[(size_t)(0 * HID + f) * HID + k1];
    float z1 = whh[(size_t)(1 * HID + f) * HID + k1];
    float n1 = whh[(size_t)(2 * HID + f) * HID + k1];
    wRZ4[(size_t)k2 * HID + f] = make_float4(r0, z0, r1, z1);
    wN2[(size_t)k2 * HID + f]  = make_float2(n0, n1);
}

// ---------------------------------------------------------------------------
// Persistent batch-sliced GRU (R13/R17-proven body): grid 256 x 1024, BG=2,
// kq-split K, early-freeze to tmax, compacted h at rows offs[bg]+t,
// nn-sorted batch pairing via perm.
// R18: k-pair-packed weights (float4+float2 per 2 k) — half the load
// instructions, same bytes, same ascending-k accumulation order =>
// bitwise-identical live h.
// XGMODE 0: x-gates from compacted xg rows. XGMODE 1: Az+Ap+b_ih.
template<int XGMODE>
__global__ __launch_bounds__(1024) void k_gru8(
        const double* __restrict__ xg,            // XGMODE0: xg; XGMODE1: Az
        const double* __restrict__ Ap,
        const float* __restrict__ bih,
        const int* __restrict__ nn,
        const int* __restrict__ offs,
        const int* __restrict__ perm,
        double* __restrict__ hout,
        const float4* __restrict__ wRZ4, const float2* __restrict__ wN2,
        const float* __restrict__ bhh)
{
    const int tid = threadIdx.x;
    const int f  = tid & 255;
    const int kq = tid >> 8;             // 0..3
    const int bA = perm[2 * blockIdx.x];
    const int bB = perm[2 * blockIdx.x + 1];

    __shared__ double hs[HID][2];        // 4 KB
    __shared__ double red[4][6][HID];    // 48 KB: [kq][gate*2+b][f]

    if (kq < 2) hs[f][kq] = 0.0;

    const int nn0 = nn[bA], nn1 = nn[bB];
    const int tmax = nn0 > nn1 ? nn0 : nn1;

    const int bq = kq;                   // batch slot for gate phase
    const int bg = (kq == 1) ? bB : bA;  // kq0 -> bA, kq1 -> bB (kq>=2 unused)
    const int nnb = (kq == 0) ? nn0 : ((kq == 1) ? nn1 : 0);
    const int offs_bg = offs[bg];
    double br = 0, bz = 0, bn = 0, bihr = 0, bihz = 0, bihn = 0;
    if (kq < 2) {
        br = (double)bhh[f]; bz = (double)bhh[HID + f]; bn = (double)bhh[2 * HID + f];
        if (XGMODE == 1) {
            bihr = (double)bih[f]; bihz = (double)bih[HID + f]; bihn = (double)bih[2 * HID + f];
        }
    }
    const float4* wrz4 = wRZ4 + (size_t)(kq * 32) * HID + f;   // 32 k-pairs/quarter
    const float2* wn2  = wN2  + (size_t)(kq * 32) * HID + f;
    const double* xbase = (XGMODE == 1)
        ? xg + (size_t)bg * GDIM + f
        : xg + (size_t)offs_bg * GDIM + f;
    double* hob = hout + (size_t)offs_bg * HID + f;
    const int kbase = kq * 64;

    __syncthreads();

    for (int t = 0; t < tmax; ++t) {
        const bool act = (kq < 2) && (t < nnb);
        // x-gate values for (bg, f), active threads only, issued early
        double xr = 0, xz = 0, xn_ = 0;
        if (act) {
            if (XGMODE == 0) {
                const double* x = xbase + (size_t)t * GDIM;
                xr = x[0]; xz = x[HID]; xn_ = x[2 * HID];
            } else {
                const double* ap = Ap + (size_t)t * GDIM + f;
                xr  = xbase[0]       + ap[0]       + bihr;
                xz  = xbase[HID]     + ap[HID]     + bihz;
                xn_ = xbase[2 * HID] + ap[2 * HID] + bihn;
            }
        }

        // MAC: K-quarter kq, both batches, 2 k per iteration (ascending k)
        double a0 = 0, a1 = 0, a2 = 0, a3 = 0, a4 = 0, a5 = 0;
        #pragma unroll 8
        for (int kk2 = 0; kk2 < 32; ++kk2) {
            float4 rz = wrz4[(size_t)kk2 * HID];
            float2 nw = wn2[(size_t)kk2 * HID];
            const int k = kbase + 2 * kk2;
            double h00 = hs[k][0],     h01 = hs[k][1];
            double h10 = hs[k + 1][0], h11 = hs[k + 1][1];
            a0 += h00 * (double)rz.x; a1 += h01 * (double)rz.x;
            a2 += h00 * (double)rz.y; a3 += h01 * (double)rz.y;
            a4 += h00 * (double)nw.x; a5 += h01 * (double)nw.x;
            a0 += h10 * (double)rz.z; a1 += h11 * (double)rz.z;
            a2 += h10 * (double)rz.w; a3 += h11 * (double)rz.w;
            a4 += h10 * (double)nw.y; a5 += h11 * (double)nw.y;
        }
        red[kq][0][f] = a0; red[kq][1][f] = a1;
        red[kq][2][f] = a2; red[kq][3][f] = a3;
        red[kq][4][f] = a4; red[kq][5][f] = a5;
        __syncthreads();

        if (act) {
            // sum K-quarters ascending-k; gate eval for batch bg, feature f
            double ar = 0, az = 0, an = 0;
            #pragma unroll
            for (int qq = 0; qq < 4; ++qq) {
                ar += red[qq][0 * 2 + bq][f];
                az += red[qq][1 * 2 + bq][f];
                an += red[qq][2 * 2 + bq][f];
            }
            double hp = hs[f][bq];
            double rg = 1.0 / (1.0 + exp(-(xr + ar + br)));
            double zg = 1.0 / (1.0 + exp(-(xz + az + bz)));
            double ng = tanh(xn_ + rg * (an + bn));
            double hn = (1.0 - zg) * ng + zg * hp;
            hs[f][bq] = hn;
            hob[(size_t)t * HID] = hn;
        }
        __syncthreads();
    }
}

// ---------------------------------------------------------------------------
// WQ[g][h] = sum_o attn_in_w[g][o] * proj[o][h]   (768x256 f32)
__global__ __launch_bounds__(256) void k_wq(
        const float* __restrict__ aiw, const float* __restrict__ proj,
        float* __restrict__ WQ)
{
    __shared__ float arow[HID];
    int g = blockIdx.x, h = threadIdx.x;
    arow[h] = aiw[(size_t)g * HID + h];
    __syncthreads();
    double acc = 0.0;
    for (int o = 0; o < HID; ++o) acc += (double)arow[o] * (double)proj[(size_t)o * HID + h];
    WQ[(size_t)g * HID + h] = (float)acc;
}

// M[h][k][d] = sum_m wo[m][h*64+d] * w1[k][m]   (4x256x64 f32)
__global__ __launch_bounds__(256) void k_m(
        const float* __restrict__ wo, const float* __restrict__ w1,
        float* __restrict__ M)
{
    __shared__ float w1row[HID];
    int k = blockIdx.x, hd = threadIdx.x;
    w1row[hd] = w1[(size_t)k * HID + hd];
    __syncthreads();
    double acc = 0.0;
    for (int m = 0; m < HID; ++m) acc += (double)w1row[m] * (double)wo[(size_t)m * HID + hd];
    M[(((size_t)(hd >> 6)) * HID + k) * HD + (hd & 63)] = (float)acc;
}

// c[k] = sum_m attn_out_b[m]*mlp_w1[k,m] + mlp_b1[k]
__global__ void k_const(const float* __restrict__ ob, const float* __restrict__ w1,
                        const float* __restrict__ b1, double* __restrict__ c)
{
    int k = threadIdx.x;
    double acc = 0.0;
    for (int m = 0; m < HID; ++m) acc += (double)ob[m] * (double)w1[k * HID + m];
    c[k] = acc + (double)b1[k];
}

// ---------------------------------------------------------------------------
// Pairs: block per (b,i); wave per j (stride 4). Compacted rows offs[b]+n.
__global__ __launch_bounds__(256) void k_pairs3(
        const float* __restrict__ QKV, const float* __restrict__ G,
        const double* __restrict__ c,
        const int* __restrict__ nn, const int* __restrict__ offs,
        const float* __restrict__ gum,
        const float* __restrict__ w2, const float* __restrict__ b2,
        float* __restrict__ adj)
{
    const int bi = blockIdx.x;
    const int b = bi / (NMAX - 1);
    const int i = bi % (NMAX - 1);
    const int nnb = nn[b];
    if (i >= nnb - 1) return;
    const int tid = threadIdx.x;
    const int lane = tid & 63;
    const int wave = tid >> 6;
    const int ofb = offs[b];
    const size_t rowi = (size_t)(ofb + i);

    double cw[4], w2r[4];
    float gir[4][4];
    #pragma unroll
    for (int q = 0; q < 4; ++q) {
        int k = lane + 64 * q;
        cw[q] = c[k];
        w2r[q] = (double)w2[k] - (double)w2[HID + k];
        #pragma unroll
        for (int h = 0; h < 4; ++h) gir[q][h] = G[rowi * 1024 + h * HID + k];
    }
    const int sh = lane >> 4, sd = (lane & 15) * 4;
    const float4 qv  = *(const float4*)&QKV[rowi * GDIM + sh * HD + sd];
    const float4 kv0 = *(const float4*)&QKV[rowi * GDIM + HID + sh * HD + sd];
    double s0 = (double)qv.x * kv0.x + (double)qv.y * kv0.y
              + (double)qv.z * kv0.z + (double)qv.w * kv0.w;
    #pragma unroll
    for (int m = 1; m < 16; m <<= 1) s0 += __shfl_xor(s0, m, 64);
    s0 *= 0.125;
    const double b2d = (double)b2[0] - (double)b2[1];

    for (int j = i + 1 + wave; j < nnb; j += 4) {
        const size_t rowj = (size_t)(ofb + j);
        const float4 kv = *(const float4*)&QKV[rowj * GDIM + HID + sh * HD + sd];
        double s1 = (double)qv.x * kv.x + (double)qv.y * kv.y
                  + (double)qv.z * kv.z + (double)qv.w * kv.w;
        #pragma unroll
        for (int m = 1; m < 16; m <<= 1) s1 += __shfl_xor(s1, m, 64);
        s1 *= 0.125;
        double mx = fmax(s0, s1);
        double e0 = exp(s0 - mx), e1 = exp(s1 - mx);
        double inv = 1.0 / (e0 + e1);
        double a0 = e0 * inv, a1 = e1 * inv;
        double a0h[4], a1h[4];
        #pragma unroll
        for (int h = 0; h < 4; ++h) {
            a0h[h] = __shfl(a0, h * 16, 64);
            a1h[h] = __shfl(a1, h * 16, 64);
        }
        double dsum = 0.0;
        #pragma unroll
        for (int q = 0; q < 4; ++q) {
            int k = lane + 64 * q;
            double pre = cw[q];
            #pragma unroll
            for (int h = 0; h < 4; ++h)
                pre += a0h[h] * (double)gir[q][h]
                     + a1h[h] * (double)G[rowj * 1024 + h * HID + k];
            if (pre > 0.0) dsum += pre * w2r[q];
        }
        #pragma unroll
        for (int m = 1; m < 64; m <<= 1) dsum += __shfl_xor(dsum, m, 64);
        if (lane == 0) {
            int p_idx = i * (2 * NMAX - i - 1) / 2 + (j - i - 1);
            const float* gp = gum + ((size_t)b * NPAIRS + p_idx) * 2;
            double d = dsum + b2d + (double)gp[0] - (double)gp[1];
            if (d >= 0.0) {
                adj[(size_t)b * NMAX * NMAX + i * NMAX + j] = 1.0f;
                adj[(size_t)b * NMAX * NMAX + j * NMAX + i] = 1.0f;
            }
        }
    }
}

__global__ void k_ws_too_small(float* adj) { adj[0] = 2.0f; }

// ---------------------------------------------------------------------------
extern "C" void kernel_launch(void* const* d_in, const int* in_sizes, int n_in,
                              void* d_out, int out_size, void* d_ws, size_t ws_size,
                              hipStream_t stream)
{
    const float* z          = (const float*)d_in[0];
    const int*   nn         = (const int*)d_in[1];
    const float* pos        = (const float*)d_in[3];
    const float* w_ih0      = (const float*)d_in[4];
    const float* w_hh0      = (const float*)d_in[5];
    const float* b_ih0      = (const float*)d_in[6];
    const float* b_hh0      = (const float*)d_in[7];
    const float* w_ih1      = (const float*)d_in[8];
    const float* w_hh1      = (const float*)d_in[9];
    const float* b_ih1      = (const float*)d_in[10];
    const float* b_hh1      = (const float*)d_in[11];
    const float* proj       = (const float*)d_in[12];
    const float* attn_in_w  = (const float*)d_in[13];
    const float* attn_in_b  = (const float*)d_in[14];
    const float* attn_out_w = (const float*)d_in[15];
    const float* attn_out_b = (const float*)d_in[16];
    const float* mlp_w1     = (const float*)d_in[17];
    const float* mlp_b1     = (const float*)d_in[18];
    const float* mlp_w2     = (const float*)d_in[19];
    const float* mlp_b2     = (const float*)d_in[20];
    const float* gum        = (const float*)d_in[21];

    float* adj = (float*)d_out;
    hipMemsetAsync(adj, 0, (size_t)out_size * sizeof(float), stream);

    // Compacted region map — NO live-data aliasing:
    //  offs  @0     (2052 B) | perm @4096 (2048 B)
    //  xg    @8192        157286400  | post-GRU1 overlay: qkv f32 @8192,
    //                                  G f32 @78651392
    //  h0/h1 @157294592   52428800
    //  wRZ40 @209723392   524288 | wN20 @210247680 262144
    //  wRZ41 @210509824   524288 | wN21 @211034112 262144
    //  WQ    @211296256   786432 | M @212082688 262144 | cbf @212344832 2048
    //  Az    @212346880   3145728 | Ap @215492608 307200  (ends 215799808)
    const size_t NEED = 215799808;
    if (ws_size < NEED) { hipLaunchKernelGGL(k_ws_too_small, dim3(1), dim3(1), 0, stream, adj); return; }

    char* ws = (char*)d_ws;
    int*    offs  = (int*)(ws);
    int*    perm  = (int*)(ws + 4096);
    double* xg    = (double*)(ws + 8192);
    double* h01   = (double*)(ws + 157294592);
    float4* wRZ40 = (float4*)(ws + 209723392);
    float2* wN20  = (float2*)(ws + 210247680);
    float4* wRZ41 = (float4*)(ws + 210509824);
    float2* wN21  = (float2*)(ws + 211034112);
    float*  WQ    = (float*)(ws + 211296256);
    float*  M     = (float*)(ws + 212082688);
    double* cbf   = (double*)(ws + 212344832);
    double* Az    = (double*)(ws + 212346880);
    double* Ap    = (double*)(ws + 215492608);
    float*  qkv   = (float*)(ws + 8192);
    float*  G     = (float*)(ws + 78651392);
    const int* nlivep = offs + 512;

    // 0) prefix-sum of nn -> offs; nn-sorted pairing -> perm
    hipLaunchKernelGGL(k_offs, dim3(1), dim3(512), 0, stream, nn, offs);
    hipLaunchKernelGGL(k_sort, dim3(1), dim3(512), 0, stream, nn, perm);
    // 1) separable layer-0 input gates: Az = z@w_ih0^T (512x768), Ap = pos@w_ih0^T
    hipLaunchKernelGGL((k_gemm5<LATENT, false, true, false, false>), dim3(8, 6), dim3(256), 0, stream,
                       (const void*)z, (long)LATENT, 0, nullptr,
                       w_ih0, LATENT, 0L, (const float*)nullptr,
                       (void*)Az, (long)GDIM, 0);
    hipLaunchKernelGGL(k_ap, dim3(NMAX), dim3(256), 0, stream, pos, w_ih0, Ap);
    // 2) GRU layer 0 (k-pair-packed weights, sorted pairing, early-freeze)
    hipLaunchKernelGGL(k_pack_v4, dim3(128), dim3(256), 0, stream, w_hh0, wRZ40, wN20);
    hipLaunchKernelGGL((k_gru8<1>), dim3(256), dim3(1024), 0, stream,
                       Az, Ap, b_ih0, nn, offs, perm, h01, wRZ40, wN20, b_hh0);
    // 3) layer-1 input gates over compacted live rows only
    hipLaunchKernelGGL((k_gemm5<HID, true, true, true, true>), dim3(400, 6), dim3(256), 0, stream,
                       (const void*)h01, (long)HID, 0, nlivep,
                       w_ih1, HID, 0L, b_ih1, (void*)xg, (long)GDIM, 0);
    // 4) GRU layer 1 (h1 overwrites dead h0; reads compacted xg)
    hipLaunchKernelGGL(k_pack_v4, dim3(128), dim3(256), 0, stream, w_hh1, wRZ41, wN21);
    hipLaunchKernelGGL((k_gru8<0>), dim3(256), dim3(1024), 0, stream,
                       xg, nullptr, nullptr, nn, offs, perm, h01, wRZ41, wN21, b_hh1);
    // 5) fused (proj @ attn_in_w), then qkv from compacted h1 (all rows live)
    hipLaunchKernelGGL(k_wq, dim3(768), dim3(256), 0, stream, attn_in_w, proj, WQ);
    hipLaunchKernelGGL((k_gemm5<HID, true, false, true, true>), dim3(400, 6), dim3(256), 0, stream,
                       (const void*)h01, (long)HID, 0, nlivep,
                       WQ, HID, 0L, attn_in_b, (void*)qkv, (long)GDIM, 0);
    // 6) M precompute + single fused G GEMM (grid.z = head, compacted rows)
    hipLaunchKernelGGL(k_m, dim3(256), dim3(256), 0, stream, attn_out_w, mlp_w1, M);
    hipLaunchKernelGGL(k_const, dim3(1), dim3(256), 0, stream, attn_out_b, mlp_w1, mlp_b1, cbf);
    hipLaunchKernelGGL((k_gemm5<HD, false, false, false, true>), dim3(400, 2, 4), dim3(256), 0, stream,
                       (const void*)(qkv + 2 * HID), (long)GDIM, HD, nlivep,
                       M, HD, (long)(HID * HD), (const float*)nullptr,
                       (void*)G, 1024L, HID);
    // 7) pairs (compacted row indexing)
    hipLaunchKernelGGL(k_pairs3, dim3(BB * (NMAX - 1)), dim3(256), 0, stream,
                       qkv, G, cbf, nn, offs, gum, mlp_w2, mlp_b2, adj);
}